// Round 1
// baseline (490.995 us; speedup 1.0000x reference)
//
#include <hip/hip_runtime.h>
#include <hip/hip_bf16.h>

typedef short s16b;
using bf16x4 = __attribute__((ext_vector_type(4))) short;
using bf16x8 = __attribute__((ext_vector_type(8))) short;
using f32x4  = __attribute__((ext_vector_type(4))) float;

#define DEVINL __device__ __forceinline__

DEVINL float bf2f(short u) {
    union { float f; unsigned u; } x;
    x.u = ((unsigned)(unsigned short)u) << 16;
    return x.f;
}
DEVINL short f2bf(float f) {   // round-to-nearest-even
    unsigned u = __builtin_bit_cast(unsigned, f);
    u += 0x7FFFu + ((u >> 16) & 1u);
    return (short)(u >> 16);
}

DEVINL f32x4 mfma16(bf16x8 a, bf16x8 b, f32x4 c) {
    return __builtin_amdgcn_mfma_f32_16x16x32_bf16(a, b, c, 0, 0, 0);
}

DEVINL void gload_lds16(const void* g, void* lds_uniform) {
    __builtin_amdgcn_global_load_lds(
        (const __attribute__((address_space(1))) char*)(const char*)g,
        (__attribute__((address_space(3))) char*)(char*)lds_uniform, 16, 0, 0);
}

// ---- LDS fragment readers (swizzled rows). LDS[row][c] = G[row][c ^ swz(row)]
DEVINL bf16x8 ldsfrag64(const s16b* base, int row, int g) {       // row stride 64B, swz=(row&3)<<4
    const char* p = (const char*)base + row * 64;
    int sw = (row & 3) << 4;
    bf16x4 lo = *(const bf16x4*)(p + ((8 * g) ^ sw));
    bf16x4 hi = *(const bf16x4*)(p + ((8 * g + 32) ^ sw));
    return __builtin_shufflevector(lo, hi, 0, 1, 2, 3, 4, 5, 6, 7);
}
DEVINL bf16x8 ldsfrag256(const s16b* base, int row, int dbyte, int g) { // row stride 256B, swz=(row&7)<<4
    const char* p = (const char*)base + row * 256;
    int sw = (row & 7) << 4;
    bf16x4 lo = *(const bf16x4*)(p + ((dbyte + 8 * g) ^ sw));
    bf16x4 hi = *(const bf16x4*)(p + ((dbyte + 8 * g + 32) ^ sw));
    return __builtin_shufflevector(lo, hi, 0, 1, 2, 3, 4, 5, 6, 7);
}
DEVINL bf16x8 ldsfrag128(const s16b* base, int row, int kbyte, int g) { // row stride 128B, swz=(row&7)<<4
    const char* p = (const char*)base + row * 128;
    int sw = (row & 7) << 4;
    bf16x4 lo = *(const bf16x4*)(p + ((kbyte + 8 * g) ^ sw));
    bf16x4 hi = *(const bf16x4*)(p + ((kbyte + 8 * g + 32) ^ sw));
    return __builtin_shufflevector(lo, hi, 0, 1, 2, 3, 4, 5, 6, 7);
}

// ---------------- RoPE tables: cos/sin [2048][64] fp32 ----------------
__global__ void k_tables(float* __restrict__ ctab, float* __restrict__ stab) {
    int idx = blockIdx.x * 256 + threadIdx.x;      // 2048*64 = 131072
    int i = idx & 63, t = idx >> 6;
    float inv = powf(10000.0f, -(float)i * (1.0f / 64.0f));
    float fr = (float)t * inv;
    ctab[idx] = cosf(fr);
    stab[idx] = sinf(fr);
}

// ---------------- x fp32 -> bf16 ----------------
__global__ void k_cvt_x(const float* __restrict__ x, s16b* __restrict__ xb) {
    int i = blockIdx.x * 256 + threadIdx.x;        // 2097152 threads, 4 elems each
    float4 v = *(const float4*)(x + (size_t)i * 4);
    bf16x4 o;
    o[0] = f2bf(v.x); o[1] = f2bf(v.y); o[2] = f2bf(v.z); o[3] = f2bf(v.w);
    *(bf16x4*)(xb + (size_t)i * 4) = o;
}

// ---------------- W [R][C] fp32 -> Wt [C][R] bf16 ----------------
__global__ void k_tcvt(const float* __restrict__ in, s16b* __restrict__ out, int R, int C) {
    __shared__ float tile[32][33];
    int tx = threadIdx.x & 31, ty = threadIdx.x >> 5;   // 32 x 8
    int c0 = blockIdx.x * 32, r0 = blockIdx.y * 32;
#pragma unroll
    for (int kk = 0; kk < 4; ++kk) {
        int r = ty + kk * 8;
        tile[r][tx] = in[(size_t)(r0 + r) * C + c0 + tx];
    }
    __syncthreads();
#pragma unroll
    for (int kk = 0; kk < 4; ++kk) {
        int r = ty + kk * 8;
        out[(size_t)(c0 + r) * R + r0 + tx] = f2bf(tile[tx][r]);
    }
}

// ---------------- GEMM mainloop (shared by both GEMMs via macro) ----------------
// A [M][2048] bf16, Bt [N][2048] bf16. 128x128 tile, 4 waves of 64x64, BK=32.
#define GEMM_MAINLOOP(A_, Bt_)                                                        \
    constexpr int Kd = 2048;                                                          \
    __shared__ s16b As[128 * 32];                                                     \
    __shared__ s16b Bs[128 * 32];                                                     \
    const int tid = threadIdx.x;                                                      \
    const int lane = tid & 63, wave = tid >> 6;                                       \
    const int g = lane >> 4, r15 = lane & 15;                                         \
    const int wm = wave & 1, wn = wave >> 1;                                          \
    const int bm = blockIdx.y * 128, bn = blockIdx.x * 128;                           \
    f32x4 acc[4][4] = {};                                                             \
    for (int k0 = 0; k0 < Kd; k0 += 32) {                                             \
        __syncthreads();                                                              \
        _Pragma("unroll")                                                             \
        for (int rr = 0; rr < 2; ++rr) {                                              \
            int uo = (rr * 256 + wave * 64) * 16;                                     \
            int o = uo + lane * 16;                                                   \
            int row = o >> 6, colb = o & 63;                                          \
            int scol = colb ^ ((row & 3) << 4);                                       \
            gload_lds16((const char*)(A_) + (size_t)(bm + row) * (Kd * 2) + k0 * 2 + scol, \
                        (char*)As + uo);                                              \
            gload_lds16((const char*)(Bt_) + (size_t)(bn + row) * (Kd * 2) + k0 * 2 + scol, \
                        (char*)Bs + uo);                                              \
        }                                                                             \
        __syncthreads();                                                              \
        bf16x8 af[4], bfr[4];                                                         \
        _Pragma("unroll")                                                             \
        for (int i = 0; i < 4; ++i) af[i] = ldsfrag64(As, wm * 64 + i * 16 + r15, g); \
        _Pragma("unroll")                                                             \
        for (int j = 0; j < 4; ++j) bfr[j] = ldsfrag64(Bs, wn * 64 + j * 16 + r15, g);\
        _Pragma("unroll")                                                             \
        for (int i = 0; i < 4; ++i)                                                   \
            _Pragma("unroll")                                                         \
            for (int j = 0; j < 4; ++j) acc[i][j] = mfma16(af[i], bfr[j], acc[i][j]); \
    }

// QKV GEMM: M=4096 (b*2048+t), N=6144 (which*2048 + h*128 + d).
// Q,K -> [B,H,T,D]; V -> transposed [B,H,D,T].
__global__ __launch_bounds__(256) void k_gemm_qkv(
    const s16b* __restrict__ A, const s16b* __restrict__ Bt,
    s16b* __restrict__ Qb, s16b* __restrict__ Kb, s16b* __restrict__ Vt) {
    GEMM_MAINLOOP(A, Bt)
    const int mb = bm + wm * 64;
    const int nb = bn + wn * 64;
#pragma unroll
    for (int i = 0; i < 4; ++i) {
#pragma unroll
        for (int j = 0; j < 4; ++j) {
            int n = nb + j * 16 + r15;
            int which = n >> 11;
            int h = (n >> 7) & 15, d = n & 127;
            int m0 = mb + i * 16 + 4 * g;
            int b = m0 >> 11, t0 = m0 & 2047;
            size_t bh = (size_t)(b * 16 + h);
            if (which == 0) {
                size_t base = (bh * 2048 + t0) * 128 + d;
#pragma unroll
                for (int e = 0; e < 4; ++e) Qb[base + (size_t)e * 128] = f2bf(acc[i][j][e]);
            } else if (which == 1) {
                size_t base = (bh * 2048 + t0) * 128 + d;
#pragma unroll
                for (int e = 0; e < 4; ++e) Kb[base + (size_t)e * 128] = f2bf(acc[i][j][e]);
            } else {
                size_t base = (bh * 128 + d) * 2048 + t0;   // t0 multiple of 4 -> aligned 8B
                bf16x4 pk;
#pragma unroll
                for (int e = 0; e < 4; ++e) pk[e] = f2bf(acc[i][j][e]);
                *(bf16x4*)(Vt + base) = pk;
            }
        }
    }
}

// Proj GEMM: M=4096, N=2048, fp32 output.
__global__ __launch_bounds__(256) void k_gemm_proj(
    const s16b* __restrict__ A, const s16b* __restrict__ Bt, float* __restrict__ Co) {
    GEMM_MAINLOOP(A, Bt)
    const int mb = bm + wm * 64;
    const int nb = bn + wn * 64;
#pragma unroll
    for (int i = 0; i < 4; ++i) {
#pragma unroll
        for (int j = 0; j < 4; ++j) {
            int n = nb + j * 16 + r15;
            int m0 = mb + i * 16 + 4 * g;
#pragma unroll
            for (int e = 0; e < 4; ++e) Co[(size_t)(m0 + e) * 2048 + n] = acc[i][j][e];
        }
    }
}

// ---------------- RoPE (in place on Q and K, [B,H,T,D]) ----------------
__global__ void k_rope(s16b* __restrict__ Qb, s16b* __restrict__ Kb,
                       const float* __restrict__ ctab, const float* __restrict__ stab) {
    int idx = blockIdx.x * 256 + threadIdx.x;   // 2*32*2048*16 = 2097152
    int i4 = idx & 15;
    int t = (idx >> 4) & 2047;
    int bh = (idx >> 15) & 31;
    int which = idx >> 20;
    s16b* P = (which ? Kb : Qb) + ((size_t)bh * 2048 + t) * 128;
    const float* cp = ctab + t * 64 + i4 * 4;
    const float* sp = stab + t * 64 + i4 * 4;
    bf16x4 a = *(bf16x4*)(P + i4 * 4);
    bf16x4 bv = *(bf16x4*)(P + i4 * 4 + 64);
    bf16x4 ra, rb;
#pragma unroll
    for (int e = 0; e < 4; ++e) {
        float c = cp[e], s = sp[e];
        float x1 = bf2f(a[e]), x2 = bf2f(bv[e]);
        ra[e] = f2bf(x1 * c - x2 * s);
        rb[e] = f2bf(x2 * c + x1 * s);
    }
    *(bf16x4*)(P + i4 * 4) = ra;
    *(bf16x4*)(P + i4 * 4 + 64) = rb;
}

// ---------------- Flash attention (swapped QK^T, causal) ----------------
// grid (16 qtiles, 32 bh). 4 waves; wave w owns q rows [qt*128+w*32, +32). KT=64.
__global__ __launch_bounds__(256) void k_attn(
    const s16b* __restrict__ Qb, const s16b* __restrict__ Kb,
    const s16b* __restrict__ Vt, s16b* __restrict__ AO) {
    __shared__ s16b Ks[64 * 128];   // [k][d], rows 256B, swz (row&7)<<4
    __shared__ s16b Vs[128 * 64];   // [d][k], rows 128B, swz (row&7)<<4
    const int tid = threadIdx.x;
    const int lane = tid & 63, wave = tid >> 6;
    const int g = lane >> 4, r15 = lane & 15;
    const int qt = blockIdx.x, bh = blockIdx.y;
    const int q0 = qt * 128 + wave * 32;
    const s16b* Qg = Qb + (size_t)bh * 2048 * 128;
    const s16b* Kg = Kb + (size_t)bh * 2048 * 128;
    const s16b* Vg = Vt + (size_t)bh * 128 * 2048;

    // hoist Q fragments: B-operand layout (col = q = l&15 based)
    bf16x8 qf[2][4];
#pragma unroll
    for (int qs = 0; qs < 2; ++qs)
#pragma unroll
        for (int ds = 0; ds < 4; ++ds) {
            const s16b* p = Qg + (size_t)(q0 + qs * 16 + r15) * 128 + ds * 32 + 4 * g;
            bf16x4 lo = *(const bf16x4*)p;
            bf16x4 hi = *(const bf16x4*)(p + 16);
            qf[qs][ds] = __builtin_shufflevector(lo, hi, 0, 1, 2, 3, 4, 5, 6, 7);
        }

    f32x4 ot[8][2] = {};               // O^T accs: [dsub][qsub]
    float m_s[2] = {-3e38f, -3e38f};
    float l_s[2] = {0.f, 0.f};
    const float scale = 0.0883883476483184f;   // 1/sqrt(128)

    const int ktiles = qt * 2 + 2;
    for (int kt = 0; kt < ktiles; ++kt) {
        const int k0 = kt * 64;
        __syncthreads();
#pragma unroll
        for (int rr = 0; rr < 4; ++rr) {
            int uo = (rr * 256 + wave * 64) * 16;
            int o = uo + lane * 16;
            {   // K tile
                int row = o >> 8, colb = o & 255;
                int scol = colb ^ ((row & 7) << 4);
                gload_lds16((const char*)Kg + (size_t)(k0 + row) * 256 + scol, (char*)Ks + uo);
            }
            {   // V^T tile
                int row = o >> 7, colb = o & 127;
                int scol = colb ^ ((row & 7) << 4);
                gload_lds16((const char*)Vg + (size_t)row * 4096 + (size_t)k0 * 2 + scol,
                            (char*)Vs + uo);
            }
        }
        __syncthreads();

        if (k0 <= q0 + 31) {   // wave-uniform causal skip
            // S^T = K . Q^T   (rows = k, cols = q)
            f32x4 st[4][2] = {};
#pragma unroll
            for (int ds = 0; ds < 4; ++ds) {
                bf16x8 kf[4];
#pragma unroll
                for (int ks = 0; ks < 4; ++ks) kf[ks] = ldsfrag256(Ks, ks * 16 + r15, ds * 64, g);
#pragma unroll
                for (int ks = 0; ks < 4; ++ks)
#pragma unroll
                    for (int qs = 0; qs < 2; ++qs)
                        st[ks][qs] = mfma16(kf[ks], qf[qs][ds], st[ks][qs]);
            }
            // scale + causal mask
#pragma unroll
            for (int ks = 0; ks < 4; ++ks)
#pragma unroll
                for (int qs = 0; qs < 2; ++qs)
#pragma unroll
                    for (int e = 0; e < 4; ++e) {
                        int kk = k0 + ks * 16 + 4 * g + e;
                        int qq = q0 + qs * 16 + r15;
                        float s = st[ks][qs][e] * scale;
                        st[ks][qs][e] = (kk <= qq) ? s : -3e38f;
                    }
            // online softmax per q-column (lane-local + 2 shfl_xor)
            float sf[2];
#pragma unroll
            for (int qs = 0; qs < 2; ++qs) {
                float mx = -3e38f;
#pragma unroll
                for (int ks = 0; ks < 4; ++ks)
#pragma unroll
                    for (int e = 0; e < 4; ++e) mx = fmaxf(mx, st[ks][qs][e]);
                mx = fmaxf(mx, __shfl_xor(mx, 16));
                mx = fmaxf(mx, __shfl_xor(mx, 32));
                float mn = fmaxf(m_s[qs], mx);
                sf[qs] = __expf(m_s[qs] - mn);
                m_s[qs] = mn;
                float sum = 0.f;
#pragma unroll
                for (int ks = 0; ks < 4; ++ks)
#pragma unroll
                    for (int e = 0; e < 4; ++e) {
                        float p = __expf(st[ks][qs][e] - mn);
                        st[ks][qs][e] = p;
                        sum += p;
                    }
                sum += __shfl_xor(sum, 16);
                sum += __shfl_xor(sum, 32);
                l_s[qs] = l_s[qs] * sf[qs] + sum;
            }
            // P -> bf16 B-frags (pure register rearrangement; C/D layout == B layout)
            bf16x8 pb[2][2];
#pragma unroll
            for (int k2 = 0; k2 < 2; ++k2)
#pragma unroll
                for (int qs = 0; qs < 2; ++qs) {
                    bf16x8 f;
#pragma unroll
                    for (int jj = 0; jj < 8; ++jj)
                        f[jj] = f2bf(st[2 * k2 + (jj >> 2)][qs][jj & 3]);
                    pb[k2][qs] = f;
                }
            // rescale O
#pragma unroll
            for (int d8 = 0; d8 < 8; ++d8)
#pragma unroll
                for (int qs = 0; qs < 2; ++qs)
#pragma unroll
                    for (int e = 0; e < 4; ++e) ot[d8][qs][e] *= sf[qs];
            // O^T += V^T . P^T
#pragma unroll
            for (int k2 = 0; k2 < 2; ++k2)
#pragma unroll
                for (int d8 = 0; d8 < 8; ++d8) {
                    bf16x8 vf = ldsfrag128(Vs, d8 * 16 + r15, k2 * 64, g);
#pragma unroll
                    for (int qs = 0; qs < 2; ++qs)
                        ot[d8][qs] = mfma16(vf, pb[k2][qs], ot[d8][qs]);
                }
        }
    }
    // write AO [B,T,C]  (C index = h*128 + d)
    int b = bh >> 4, h = bh & 15;
#pragma unroll
    for (int qs = 0; qs < 2; ++qs) {
        float inv = 1.0f / l_s[qs];
        int q = q0 + qs * 16 + r15;
#pragma unroll
        for (int d8 = 0; d8 < 8; ++d8) {
            bf16x4 pk;
#pragma unroll
            for (int e = 0; e < 4; ++e) pk[e] = f2bf(ot[d8][qs][e] * inv);
            size_t off = ((size_t)(b * 2048 + q)) * 2048 + h * 128 + d8 * 16 + 4 * g;
            *(bf16x4*)(AO + off) = pk;
        }
    }
}

extern "C" void kernel_launch(void* const* d_in, const int* in_sizes, int n_in,
                              void* d_out, int out_size, void* d_ws, size_t ws_size,
                              hipStream_t stream) {
    const float* x = (const float*)d_in[0];
    const float* Wqkv = (const float*)d_in[1];
    const float* Wproj = (const float*)d_in[2];
    float* out = (float*)d_out;

    char* ws = (char*)d_ws;
    float* ctab = (float*)ws;
    float* stab = ctab + 2048 * 64;
    size_t off = 1048576;
    s16b* xb = (s16b*)(ws + off); off += 16777216;        // x bf16 [4096][2048]; reused as AO
    s16b* wqkvt = (s16b*)(ws + off); off += 25165824;     // [6144][2048] bf16
    s16b* wprojt = (s16b*)(ws + off); off += 8388608;     // [2048][2048] bf16
    s16b* Qb = (s16b*)(ws + off); off += 16777216;        // [2,16,2048,128] bf16
    s16b* Kb = (s16b*)(ws + off); off += 16777216;
    s16b* Vt = (s16b*)(ws + off); off += 16777216;        // [2,16,128,2048] bf16
    s16b* AO = xb;   // alias: xb dead after QKV GEMM

    k_tables<<<dim3(512), dim3(256), 0, stream>>>(ctab, stab);
    k_cvt_x<<<dim3(8192), dim3(256), 0, stream>>>(x, xb);
    k_tcvt<<<dim3(192, 64), dim3(256), 0, stream>>>(Wqkv, wqkvt, 2048, 6144);
    k_tcvt<<<dim3(64, 64), dim3(256), 0, stream>>>(Wproj, wprojt, 2048, 2048);
    k_gemm_qkv<<<dim3(48, 32), dim3(256), 0, stream>>>(xb, wqkvt, Qb, Kb, Vt);
    k_rope<<<dim3(8192), dim3(256), 0, stream>>>(Qb, Kb, ctab, stab);
    k_attn<<<dim3(16, 32), dim3(256), 0, stream>>>(Qb, Kb, Vt, AO);
    k_gemm_proj<<<dim3(16, 32), dim3(256), 0, stream>>>(AO, wprojt, out);
}

// Round 2
// 296.404 us; speedup vs baseline: 1.6565x; 1.6565x over previous
//
#include <hip/hip_runtime.h>
#include <hip/hip_bf16.h>

typedef short s16b;
using bf16x4 = __attribute__((ext_vector_type(4))) short;
using bf16x8 = __attribute__((ext_vector_type(8))) short;
using f32x4  = __attribute__((ext_vector_type(4))) float;

#define DEVINL __device__ __forceinline__

DEVINL float bf2f(short u) {
    union { float f; unsigned u; } x;
    x.u = ((unsigned)(unsigned short)u) << 16;
    return x.f;
}
DEVINL short f2bf(float f) {   // round-to-nearest-even
    unsigned u = __builtin_bit_cast(unsigned, f);
    u += 0x7FFFu + ((u >> 16) & 1u);
    return (short)(u >> 16);
}

DEVINL f32x4 mfma16(bf16x8 a, bf16x8 b, f32x4 c) {
    return __builtin_amdgcn_mfma_f32_16x16x32_bf16(a, b, c, 0, 0, 0);
}

DEVINL void gload_lds16(const void* g, void* lds_uniform) {
    __builtin_amdgcn_global_load_lds(
        (const __attribute__((address_space(1))) char*)(const char*)g,
        (__attribute__((address_space(3))) char*)(char*)lds_uniform, 16, 0, 0);
}

// stored position of k within a 32-element K-group:
// chunk order [0-3,16-19,4-7,20-23,8-11,24-27,12-15,28-31]
DEVINL int perm32(int k) {
    return ((k >> 2) & 3) * 8 + ((k >> 4) & 1) * 4 + (k & 3);
}

// LDS frag read, 128B rows, 8 slots of 16B, swizzle slot^=(row&7). One ds_read_b128.
DEVINL bf16x8 lds128(const s16b* base, int row, int ks, int g) {
    const char* p = (const char*)base + row * 128 + ((((ks << 2) + g) ^ (row & 7)) << 4);
    return *(const bf16x8*)p;
}
// LDS frag read, 256B rows, 16 slots, swizzle low 3 slot bits.
DEVINL bf16x8 lds256(const s16b* base, int row, int ds, int g) {
    const char* p = (const char*)base + row * 256 + ((((ds << 2) + g) ^ (row & 7)) << 4);
    return *(const bf16x8*)p;
}

// ---------------- RoPE tables: cos/sin [2048][64] fp32 ----------------
__global__ void k_tables(float* __restrict__ ctab, float* __restrict__ stab) {
    int idx = blockIdx.x * 256 + threadIdx.x;      // 2048*64 = 131072
    int i = idx & 63, t = idx >> 6;
    float inv = powf(10000.0f, -(float)i * (1.0f / 64.0f));
    float fr = (float)t * inv;
    ctab[idx] = cosf(fr);
    stab[idx] = sinf(fr);
}

// ---------------- x fp32 -> bf16, K-permuted rows ----------------
__global__ void k_cvt_x(const float* __restrict__ x, s16b* __restrict__ xb) {
    int idx = blockIdx.x * 256 + threadIdx.x;        // 2097152 threads, 4 elems each
    int p = idx * 4;                                  // stored position
    int row = p >> 11, pc = p & 2047;
    int grp = pc >> 5, sp = pc & 31;
    int c = sp >> 3, half = (sp >> 2) & 1;
    int ksrc = grp * 32 + half * 16 + c * 4;          // source k (4 contiguous)
    float4 v = *(const float4*)(x + (size_t)row * 2048 + ksrc);
    bf16x4 o;
    o[0] = f2bf(v.x); o[1] = f2bf(v.y); o[2] = f2bf(v.z); o[3] = f2bf(v.w);
    *(bf16x4*)(xb + (size_t)row * 2048 + pc) = o;
}

// ---------------- W [R][C] fp32 -> Wt [C][R] bf16, K(=R)-permuted ----------------
__global__ void k_tcvt(const float* __restrict__ in, s16b* __restrict__ out, int R, int C) {
    __shared__ float tile[32][33];
    int tx = threadIdx.x & 31, ty = threadIdx.x >> 5;   // 32 x 8
    int c0 = blockIdx.x * 32, r0 = blockIdx.y * 32;     // r0 multiple of 32
#pragma unroll
    for (int kk = 0; kk < 4; ++kk) {
        int r = ty + kk * 8;
        tile[r][tx] = in[(size_t)(r0 + r) * C + c0 + tx];
    }
    __syncthreads();
#pragma unroll
    for (int kk = 0; kk < 4; ++kk) {
        int r = ty + kk * 8;
        out[(size_t)(c0 + r) * R + r0 + perm32(tx)] = f2bf(tile[tx][r]);
    }
}

// ---------------- GEMM mainloop: 128x128 tile, BK=64, 4 waves ----------------
// A [M][2048] bf16 K-permuted, Bt [N][2048] bf16 K-permuted.
#define GEMM_MAINLOOP(A_, Bt_)                                                        \
    constexpr int Kd = 2048;                                                          \
    __shared__ alignas(16) s16b As[128 * 64];                                         \
    __shared__ alignas(16) s16b Bs[128 * 64];                                         \
    const int tid = threadIdx.x;                                                      \
    const int lane = tid & 63, wave = tid >> 6;                                       \
    const int g = lane >> 4, r15 = lane & 15;                                         \
    const int wm = wave & 1, wn = wave >> 1;                                          \
    const int nbx = gridDim.x;                                                        \
    const int nwg = gridDim.x * gridDim.y;                                            \
    const int bid = blockIdx.y * nbx + blockIdx.x;                                    \
    const int sbid = (bid & 7) * (nwg >> 3) + (bid >> 3);                             \
    const int bm = (sbid / nbx) * 128, bn = (sbid % nbx) * 128;                       \
    f32x4 acc[4][4] = {};                                                             \
    for (int k0 = 0; k0 < Kd; k0 += 64) {                                             \
        __syncthreads();                                                              \
        _Pragma("unroll")                                                             \
        for (int rr = 0; rr < 4; ++rr) {                                              \
            int uo = (rr * 256 + wave * 64) * 16;                                     \
            int o = uo + lane * 16;                                                   \
            int row = o >> 7, sl = (o >> 4) & 7;                                      \
            int sg = (sl ^ (row & 7)) << 4;                                           \
            gload_lds16((const char*)(A_) + (size_t)(bm + row) * 4096 + k0 * 2 + sg,  \
                        (char*)As + uo);                                              \
            gload_lds16((const char*)(Bt_) + (size_t)(bn + row) * 4096 + k0 * 2 + sg, \
                        (char*)Bs + uo);                                              \
        }                                                                             \
        __syncthreads();                                                              \
        _Pragma("unroll")                                                             \
        for (int ks = 0; ks < 2; ++ks) {                                              \
            bf16x8 af[4], bfr[4];                                                     \
            _Pragma("unroll")                                                         \
            for (int i = 0; i < 4; ++i) af[i] = lds128(As, wm * 64 + i * 16 + r15, ks, g); \
            _Pragma("unroll")                                                         \
            for (int j = 0; j < 4; ++j) bfr[j] = lds128(Bs, wn * 64 + j * 16 + r15, ks, g); \
            _Pragma("unroll")                                                         \
            for (int i = 0; i < 4; ++i)                                               \
                _Pragma("unroll")                                                     \
                for (int j = 0; j < 4; ++j) acc[i][j] = mfma16(af[i], bfr[j], acc[i][j]); \
        }                                                                             \
    }

// QKV GEMM: M=4096 (b*2048+t), N=6144 (which*2048 + h*128 + d).
// Q,K -> [B,H,T,D] plain; V -> [B,H,D,T] with t-permuted columns.
__global__ __launch_bounds__(256) void k_gemm_qkv(
    const s16b* __restrict__ A, const s16b* __restrict__ Bt,
    s16b* __restrict__ Qb, s16b* __restrict__ Kb, s16b* __restrict__ Vt) {
    GEMM_MAINLOOP(A, Bt)
    const int mb = bm + wm * 64;
    const int nb = bn + wn * 64;
#pragma unroll
    for (int i = 0; i < 4; ++i) {
#pragma unroll
        for (int j = 0; j < 4; ++j) {
            int n = nb + j * 16 + r15;
            int which = n >> 11;
            int h = (n >> 7) & 15, d = n & 127;
            int m0 = mb + i * 16 + 4 * g;
            int b = m0 >> 11, t0 = m0 & 2047;
            size_t bh = (size_t)(b * 16 + h);
            if (which == 0) {
                size_t base = (bh * 2048 + t0) * 128 + d;
#pragma unroll
                for (int e = 0; e < 4; ++e) Qb[base + (size_t)e * 128] = f2bf(acc[i][j][e]);
            } else if (which == 1) {
                size_t base = (bh * 2048 + t0) * 128 + d;
#pragma unroll
                for (int e = 0; e < 4; ++e) Kb[base + (size_t)e * 128] = f2bf(acc[i][j][e]);
            } else {
                int pt = (t0 & ~31) + perm32(t0 & 31);   // t-permuted, 4-aligned
                size_t base = (bh * 128 + d) * 2048 + pt;
                bf16x4 pk;
#pragma unroll
                for (int e = 0; e < 4; ++e) pk[e] = f2bf(acc[i][j][e]);
                *(bf16x4*)(Vt + base) = pk;
            }
        }
    }
}

// Proj GEMM: M=4096, N=2048, fp32 output.
__global__ __launch_bounds__(256) void k_gemm_proj(
    const s16b* __restrict__ A, const s16b* __restrict__ Bt, float* __restrict__ Co) {
    GEMM_MAINLOOP(A, Bt)
    const int mb = bm + wm * 64;
    const int nb = bn + wn * 64;
#pragma unroll
    for (int i = 0; i < 4; ++i) {
#pragma unroll
        for (int j = 0; j < 4; ++j) {
            int n = nb + j * 16 + r15;
            int m0 = mb + i * 16 + 4 * g;
#pragma unroll
            for (int e = 0; e < 4; ++e) Co[(size_t)(m0 + e) * 2048 + n] = acc[i][j][e];
        }
    }
}

// ---------------- RoPE: Q in place (plain); K -> Kp (d-permuted) ----------------
__global__ void k_rope(s16b* __restrict__ Qb, const s16b* __restrict__ Kb,
                       s16b* __restrict__ Kp,
                       const float* __restrict__ ctab, const float* __restrict__ stab) {
    int idx = blockIdx.x * 256 + threadIdx.x;   // 2*32*2048*16 = 2097152
    int i4 = idx & 15;
    int t = (idx >> 4) & 2047;
    int bh = (idx >> 15) & 31;
    int which = idx >> 20;
    int d = i4 * 4;                 // [0,64)
    const float* cp = ctab + t * 64 + d;
    const float* sp = stab + t * 64 + d;
    size_t rowoff = ((size_t)bh * 2048 + t) * 128;
    if (which == 0) {               // Q in place
        s16b* P = Qb + rowoff;
        bf16x4 a = *(bf16x4*)(P + d);
        bf16x4 bv = *(bf16x4*)(P + d + 64);
        bf16x4 ra, rb;
#pragma unroll
        for (int e = 0; e < 4; ++e) {
            float c = cp[e], s = sp[e];
            float x1 = bf2f(a[e]), x2 = bf2f(bv[e]);
            ra[e] = f2bf(x1 * c - x2 * s);
            rb[e] = f2bf(x2 * c + x1 * s);
        }
        *(bf16x4*)(P + d) = ra;
        *(bf16x4*)(P + d + 64) = rb;
    } else {                        // K: read plain, write permuted
        const s16b* Pi = Kb + rowoff;
        s16b* Po = Kp + rowoff;
        bf16x4 a = *(const bf16x4*)(Pi + d);
        bf16x4 bv = *(const bf16x4*)(Pi + d + 64);
        bf16x4 ra, rb;
#pragma unroll
        for (int e = 0; e < 4; ++e) {
            float c = cp[e], s = sp[e];
            float x1 = bf2f(a[e]), x2 = bf2f(bv[e]);
            ra[e] = f2bf(x1 * c - x2 * s);
            rb[e] = f2bf(x2 * c + x1 * s);
        }
        int d2 = d + 64;
        int pd  = (d  & ~31) + perm32(d  & 31);
        int pd2 = (d2 & ~31) + perm32(d2 & 31);
        *(bf16x4*)(Po + pd) = ra;
        *(bf16x4*)(Po + pd2) = rb;
    }
}

// ---------------- Flash attention (swapped QK^T, causal) ----------------
// grid (32 bh, 16 qtiles; qt = 15 - blockIdx.y so heavy blocks dispatch first).
__global__ __launch_bounds__(256) void k_attn(
    const s16b* __restrict__ Qb, const s16b* __restrict__ Kp,
    const s16b* __restrict__ Vt, s16b* __restrict__ AO) {
    __shared__ alignas(16) s16b Ks[64 * 128];   // [k][d-perm], 256B rows, 16 slots
    __shared__ alignas(16) s16b Vs[128 * 64];   // [d][t-perm], 128B rows, 8 slots
    const int tid = threadIdx.x;
    const int lane = tid & 63, wave = tid >> 6;
    const int g = lane >> 4, r15 = lane & 15;
    const int bh = blockIdx.x, qt = 15 - blockIdx.y;
    const int q0 = qt * 128 + wave * 32;
    const s16b* Qg = Qb + (size_t)bh * 2048 * 128;
    const char* Kg = (const char*)(Kp + (size_t)bh * 2048 * 128);
    const char* Vg = (const char*)(Vt + (size_t)bh * 128 * 2048);

    // hoist Q fragments (B-operand; global plain layout, 2x8B each)
    bf16x8 qf[2][4];
#pragma unroll
    for (int qs = 0; qs < 2; ++qs)
#pragma unroll
        for (int ds = 0; ds < 4; ++ds) {
            const s16b* p = Qg + (size_t)(q0 + qs * 16 + r15) * 128 + ds * 32 + 4 * g;
            bf16x4 lo = *(const bf16x4*)p;
            bf16x4 hi = *(const bf16x4*)(p + 16);
            qf[qs][ds] = __builtin_shufflevector(lo, hi, 0, 1, 2, 3, 4, 5, 6, 7);
        }

    f32x4 ot[8][2] = {};               // O^T accs: [dsub][qsub]
    float m_s[2] = {-3e38f, -3e38f};
    float l_s[2] = {0.f, 0.f};
    const float scale = 0.0883883476483184f;   // 1/sqrt(128)

    const int ktiles = qt * 2 + 2;
    for (int kt = 0; kt < ktiles; ++kt) {
        const int k0 = kt * 64;
        __syncthreads();
#pragma unroll
        for (int rr = 0; rr < 4; ++rr) {
            int uo = (rr * 256 + wave * 64) * 16;
            int o = uo + lane * 16;
            {   // K tile: 256B rows, 16 slots, swizzle low 3 slot bits
                int row = o >> 8, sl = (o >> 4) & 15;
                int sg = (sl ^ (row & 7)) << 4;
                gload_lds16(Kg + (size_t)(k0 + row) * 256 + sg, (char*)Ks + uo);
            }
            {   // V^T tile: 128B rows, 8 slots
                int row = o >> 7, sl = (o >> 4) & 7;
                int sg = (sl ^ (row & 7)) << 4;
                gload_lds16(Vg + (size_t)row * 4096 + (size_t)k0 * 2 + sg, (char*)Vs + uo);
            }
        }
        __syncthreads();

        if (k0 <= q0 + 31) {   // wave-uniform causal skip
            // S^T = K . Q^T   (rows = k, cols = q)
            f32x4 st[4][2] = {};
#pragma unroll
            for (int ds = 0; ds < 4; ++ds) {
#pragma unroll
                for (int ks = 0; ks < 4; ++ks) {
                    bf16x8 kf = lds256(Ks, ks * 16 + r15, ds, g);
#pragma unroll
                    for (int qs = 0; qs < 2; ++qs)
                        st[ks][qs] = mfma16(kf, qf[qs][ds], st[ks][qs]);
                }
            }
            // scale + causal mask
#pragma unroll
            for (int ks = 0; ks < 4; ++ks)
#pragma unroll
                for (int qs = 0; qs < 2; ++qs)
#pragma unroll
                    for (int e = 0; e < 4; ++e) {
                        int kk = k0 + ks * 16 + 4 * g + e;
                        int qq = q0 + qs * 16 + r15;
                        float s = st[ks][qs][e] * scale;
                        st[ks][qs][e] = (kk <= qq) ? s : -3e38f;
                    }
            // online softmax per q-column (lane-local + 2 shfl_xor)
            float sf[2];
#pragma unroll
            for (int qs = 0; qs < 2; ++qs) {
                float mx = -3e38f;
#pragma unroll
                for (int ks = 0; ks < 4; ++ks)
#pragma unroll
                    for (int e = 0; e < 4; ++e) mx = fmaxf(mx, st[ks][qs][e]);
                mx = fmaxf(mx, __shfl_xor(mx, 16));
                mx = fmaxf(mx, __shfl_xor(mx, 32));
                float mn = fmaxf(m_s[qs], mx);
                sf[qs] = __expf(m_s[qs] - mn);
                m_s[qs] = mn;
                float sum = 0.f;
#pragma unroll
                for (int ks = 0; ks < 4; ++ks)
#pragma unroll
                    for (int e = 0; e < 4; ++e) {
                        float p = __expf(st[ks][qs][e] - mn);
                        st[ks][qs][e] = p;
                        sum += p;
                    }
                sum += __shfl_xor(sum, 16);
                sum += __shfl_xor(sum, 32);
                l_s[qs] = l_s[qs] * sf[qs] + sum;
            }
            // P -> bf16 B-frags (register-only; C/D layout == B-operand layout)
            bf16x8 pb[2][2];
#pragma unroll
            for (int k2 = 0; k2 < 2; ++k2)
#pragma unroll
                for (int qs = 0; qs < 2; ++qs) {
                    bf16x8 f;
#pragma unroll
                    for (int jj = 0; jj < 8; ++jj)
                        f[jj] = f2bf(st[2 * k2 + (jj >> 2)][qs][jj & 3]);
                    pb[k2][qs] = f;
                }
            // rescale O
#pragma unroll
            for (int d8 = 0; d8 < 8; ++d8)
#pragma unroll
                for (int qs = 0; qs < 2; ++qs)
#pragma unroll
                    for (int e = 0; e < 4; ++e) ot[d8][qs][e] *= sf[qs];
            // O^T += V^T . P^T
#pragma unroll
            for (int k2 = 0; k2 < 2; ++k2)
#pragma unroll
                for (int d8 = 0; d8 < 8; ++d8) {
                    bf16x8 vf = lds128(Vs, d8 * 16 + r15, k2, g);
#pragma unroll
                    for (int qs = 0; qs < 2; ++qs)
                        ot[d8][qs] = mfma16(vf, pb[k2][qs], ot[d8][qs]);
                }
        }
    }
    // write AO [B,T,C] with C-permuted columns (proj GEMM A-operand layout)
    int b = bh >> 4, h = bh & 15;
#pragma unroll
    for (int qs = 0; qs < 2; ++qs) {
        float inv = 1.0f / l_s[qs];
        int q = q0 + qs * 16 + r15;
#pragma unroll
        for (int d8 = 0; d8 < 8; ++d8) {
            bf16x4 pk;
#pragma unroll
            for (int e = 0; e < 4; ++e) pk[e] = f2bf(ot[d8][qs][e] * inv);
            size_t off = ((size_t)(b * 2048 + q)) * 2048
                       + h * 128 + (d8 >> 1) * 32 + g * 8 + (d8 & 1) * 4;
            *(bf16x4*)(AO + off) = pk;
        }
    }
}

extern "C" void kernel_launch(void* const* d_in, const int* in_sizes, int n_in,
                              void* d_out, int out_size, void* d_ws, size_t ws_size,
                              hipStream_t stream) {
    const float* x = (const float*)d_in[0];
    const float* Wqkv = (const float*)d_in[1];
    const float* Wproj = (const float*)d_in[2];
    float* out = (float*)d_out;

    char* ws = (char*)d_ws;
    float* ctab = (float*)ws;
    float* stab = ctab + 2048 * 64;
    size_t off = 1048576;
    s16b* xb = (s16b*)(ws + off); off += 16777216;        // x bf16 K-perm; reused as AO
    s16b* wqkvt = (s16b*)(ws + off); off += 25165824;     // [6144][2048] bf16 K-perm; reused as Kp
    s16b* wprojt = (s16b*)(ws + off); off += 8388608;     // [2048][2048] bf16 K-perm
    s16b* Qb = (s16b*)(ws + off); off += 16777216;        // [2,16,2048,128] plain
    s16b* Kb = (s16b*)(ws + off); off += 16777216;        // plain (pre-RoPE)
    s16b* Vt = (s16b*)(ws + off); off += 16777216;        // [2,16,128,2048] t-perm
    s16b* AO = xb;      // alias: xb dead after QKV GEMM
    s16b* Kp = wqkvt;   // alias: wqkvt dead after QKV GEMM (RoPE'd K, d-perm)

    k_tables<<<dim3(512), dim3(256), 0, stream>>>(ctab, stab);
    k_cvt_x<<<dim3(8192), dim3(256), 0, stream>>>(x, xb);
    k_tcvt<<<dim3(192, 64), dim3(256), 0, stream>>>(Wqkv, wqkvt, 2048, 6144);
    k_tcvt<<<dim3(64, 64), dim3(256), 0, stream>>>(Wproj, wprojt, 2048, 2048);
    k_gemm_qkv<<<dim3(48, 32), dim3(256), 0, stream>>>(xb, wqkvt, Qb, Kb, Vt);
    k_rope<<<dim3(8192), dim3(256), 0, stream>>>(Qb, Kb, Kp, ctab, stab);
    k_attn<<<dim3(32, 16), dim3(256), 0, stream>>>(Qb, Kp, Vt, AO);
    k_gemm_proj<<<dim3(16, 32), dim3(256), 0, stream>>>(AO, wprojt, out);
}

// Round 3
// 293.728 us; speedup vs baseline: 1.6716x; 1.0091x over previous
//
#include <hip/hip_runtime.h>
#include <hip/hip_bf16.h>

typedef short s16b;
using bf16x4 = __attribute__((ext_vector_type(4))) short;
using bf16x8 = __attribute__((ext_vector_type(8))) short;
using f32x4  = __attribute__((ext_vector_type(4))) float;

#define DEVINL __device__ __forceinline__

DEVINL float bf2f(short u) {
    union { float f; unsigned u; } x;
    x.u = ((unsigned)(unsigned short)u) << 16;
    return x.f;
}
DEVINL short f2bf(float f) {   // round-to-nearest-even
    unsigned u = __builtin_bit_cast(unsigned, f);
    u += 0x7FFFu + ((u >> 16) & 1u);
    return (short)(u >> 16);
}

DEVINL f32x4 mfma16(bf16x8 a, bf16x8 b, f32x4 c) {
    return __builtin_amdgcn_mfma_f32_16x16x32_bf16(a, b, c, 0, 0, 0);
}

DEVINL void gload_lds16(const void* g, void* lds_uniform) {
    __builtin_amdgcn_global_load_lds(
        (const __attribute__((address_space(1))) char*)(const char*)g,
        (__attribute__((address_space(3))) char*)(char*)lds_uniform, 16, 0, 0);
}

// stored position of k within a 32-element K-group:
// chunk order [0-3,16-19,4-7,20-23,8-11,24-27,12-15,28-31]
DEVINL int perm32(int k) {
    return ((k >> 2) & 3) * 8 + ((k >> 4) & 1) * 4 + (k & 3);
}

// LDS frag read, 128B rows, 8 slots of 16B, swizzle slot^=(row&7). (attn kernels)
DEVINL bf16x8 lds128(const s16b* base, int row, int ks, int g) {
    const char* p = (const char*)base + row * 128 + ((((ks << 2) + g) ^ (row & 7)) << 4);
    return *(const bf16x8*)p;
}
// LDS frag read, 256B rows, 16 slots, swizzle low 3 slot bits.
DEVINL bf16x8 lds256(const s16b* base, int row, int ds, int g) {
    const char* p = (const char*)base + row * 256 + ((((ds << 2) + g) ^ (row & 7)) << 4);
    return *(const bf16x8*)p;
}

// ---------------- RoPE tables: cos/sin [2048][64] fp32 ----------------
__global__ void k_tables(float* __restrict__ ctab, float* __restrict__ stab) {
    int idx = blockIdx.x * 256 + threadIdx.x;      // 2048*64 = 131072
    int i = idx & 63, t = idx >> 6;
    float inv = powf(10000.0f, -(float)i * (1.0f / 64.0f));
    float fr = (float)t * inv;
    ctab[idx] = cosf(fr);
    stab[idx] = sinf(fr);
}

// ---------------- x fp32 -> bf16, K-permuted rows ----------------
__global__ void k_cvt_x(const float* __restrict__ x, s16b* __restrict__ xb) {
    int idx = blockIdx.x * 256 + threadIdx.x;        // 2097152 threads, 4 elems each
    int p = idx * 4;                                  // stored position
    int row = p >> 11, pc = p & 2047;
    int grp = pc >> 5, sp = pc & 31;
    int c = sp >> 3, half = (sp >> 2) & 1;
    int ksrc = grp * 32 + half * 16 + c * 4;          // source k (4 contiguous)
    float4 v = *(const float4*)(x + (size_t)row * 2048 + ksrc);
    bf16x4 o;
    o[0] = f2bf(v.x); o[1] = f2bf(v.y); o[2] = f2bf(v.z); o[3] = f2bf(v.w);
    *(bf16x4*)(xb + (size_t)row * 2048 + pc) = o;
}

// ---------------- W [R][C] fp32 -> Wt [C][R] bf16, K(=R)-permuted ----------------
__global__ void k_tcvt(const float* __restrict__ in, s16b* __restrict__ out, int R, int C) {
    __shared__ float tile[32][33];
    int tx = threadIdx.x & 31, ty = threadIdx.x >> 5;   // 32 x 8
    int c0 = blockIdx.x * 32, r0 = blockIdx.y * 32;     // r0 multiple of 32
#pragma unroll
    for (int kk = 0; kk < 4; ++kk) {
        int r = ty + kk * 8;
        tile[r][tx] = in[(size_t)(r0 + r) * C + c0 + tx];
    }
    __syncthreads();
#pragma unroll
    for (int kk = 0; kk < 4; ++kk) {
        int r = ty + kk * 8;
        out[(size_t)(c0 + r) * R + r0 + perm32(tx)] = f2bf(tile[tx][r]);
    }
}

// ================ 8-phase GEMM mainloop: BM=128, BN=256, BK=64, 8 waves ================
// A [M][2048] bf16 K-perm, Bt [N][2048] bf16 K-perm.
// LDS (96KB): A[buf][kh]: 8KB blocks at buf*16384+kh*8192 (128 rows x 64B, 4 slots XOR row&3)
//             B[buf][kh]: 16KB blocks at 32768 + buf*32768 + kh*16384 (256 rows x 64B)
// Halves per K-tile (order): o0=B-k0(2 loads) o1=A-k0(1) o2=B-k1(2) o3=A-k1(1); stagger S=6.
// Waits: vmcnt(5) at phases 4/8 (3 newest halves in flight), vmcnt(0) at final p4.
#define STG(H)                                                                         \
  { int tau_ = (H) >> 2, oo_ = (H) & 3;                                                \
    int skh_ = oo_ >> 1, sbuf_ = tau_ & 1;                                             \
    int koff_ = tau_ * 128 + skh_ * 64;                                                \
    if (oo_ & 1) {                                                                     \
      gload_lds16(srcA + koff_, lds + sbuf_ * 16384 + skh_ * 8192 + wave * 1024);      \
    } else {                                                                           \
      gload_lds16(srcB0 + koff_, lds + 32768 + sbuf_ * 32768 + skh_ * 16384 + wave * 1024); \
      gload_lds16(srcB1 + koff_, lds + 32768 + sbuf_ * 32768 + skh_ * 16384 + 8192 + wave * 1024); \
    } }

#define PH(BUF, KH, RH, NEWB, H, WAITN)                                                \
  {                                                                                    \
    if (NEWB) {                                                                        \
      _Pragma("unroll")                                                                \
      for (int fj = 0; fj < 4; ++fj)                                                   \
        bfr[fj] = *(const bf16x8*)(lds + 32768 + (BUF) * 32768 + (KH) * 16384          \
                     + (wn * 64 + fj * 16 + r15) * 64 + sw16);                         \
    }                                                                                  \
    _Pragma("unroll")                                                                  \
    for (int fi = 0; fi < 2; ++fi)                                                     \
      af[fi] = *(const bf16x8*)(lds + (BUF) * 16384 + (KH) * 8192                      \
                  + (wm * 64 + (RH) * 32 + fi * 16 + r15) * 64 + sw16);                \
    if ((H) < 128) STG(H)                                                              \
    if ((WAITN) == 5) { asm volatile("s_waitcnt vmcnt(5)" ::: "memory");               \
                        __builtin_amdgcn_sched_barrier(0); }                           \
    else if ((WAITN) == 0) { asm volatile("s_waitcnt vmcnt(0)" ::: "memory");          \
                        __builtin_amdgcn_sched_barrier(0); }                           \
    __builtin_amdgcn_s_barrier();                                                      \
    asm volatile("s_waitcnt lgkmcnt(0)" ::: "memory");                                 \
    __builtin_amdgcn_sched_barrier(0);                                                 \
    __builtin_amdgcn_s_setprio(1);                                                     \
    _Pragma("unroll")                                                                  \
    for (int fi = 0; fi < 2; ++fi)                                                     \
      _Pragma("unroll")                                                                \
      for (int fj = 0; fj < 4; ++fj)                                                   \
        acc[(RH) * 2 + fi][fj] = mfma16(af[fi], bfr[fj], acc[(RH) * 2 + fi][fj]);      \
    __builtin_amdgcn_s_setprio(0);                                                     \
    __builtin_amdgcn_s_barrier();                                                      \
  }

#define GEMM8_MAINLOOP(A_, B_)                                                         \
    __shared__ __attribute__((aligned(16))) char lds[98304];                           \
    const int tid = threadIdx.x;                                                       \
    const int lane = tid & 63, wave = tid >> 6;                                        \
    const int g = lane >> 4, r15 = lane & 15;                                          \
    const int wm = wave >> 2, wn = wave & 3;                                           \
    const int sw16 = (g ^ (r15 & 3)) << 4;                                             \
    const int linA = wave * 1024 + lane * 16;                                          \
    const int rwA = linA >> 6, slA = (linA >> 4) & 3;                                  \
    const char* srcA = (const char*)(A_) + (size_t)(bm + rwA) * 4096                   \
                       + ((slA ^ (rwA & 3)) << 4);                                     \
    const int rwB0 = linA >> 6, slB0 = slA;                                            \
    const char* srcB0 = (const char*)(B_) + (size_t)(bn + rwB0) * 4096                 \
                       + ((slB0 ^ (rwB0 & 3)) << 4);                                   \
    const int linB1 = 8192 + linA;                                                     \
    const int rwB1 = linB1 >> 6, slB1 = (linB1 >> 4) & 3;                              \
    const char* srcB1 = (const char*)(B_) + (size_t)(bn + rwB1) * 4096                 \
                       + ((slB1 ^ (rwB1 & 3)) << 4);                                   \
    f32x4 acc[4][4] = {};                                                              \
    bf16x8 af[2], bfr[4];                                                              \
    STG(0) STG(1) STG(2) STG(3) STG(4) STG(5) STG(6)                                  \
    asm volatile("s_waitcnt vmcnt(5)" ::: "memory");                                   \
    __builtin_amdgcn_sched_barrier(0);                                                 \
    __builtin_amdgcn_s_barrier();                                                      \
    for (int i = 0; i < 16; ++i) {                                                     \
        int hb = 8 * i + 6;                                                            \
        int w4 = (i == 15) ? 0 : 5;                                                    \
        int w8 = (i == 15) ? -1 : 5;                                                   \
        PH(0, 0, 0, true,  hb + 1, -1)                                                 \
        PH(0, 0, 1, false, hb + 2, -1)                                                 \
        PH(0, 1, 0, true,  hb + 3, -1)                                                 \
        PH(0, 1, 1, false, hb + 4, w4)                                                 \
        PH(1, 0, 0, true,  hb + 5, -1)                                                 \
        PH(1, 0, 1, false, hb + 6, -1)                                                 \
        PH(1, 1, 0, true,  hb + 7, -1)                                                 \
        PH(1, 1, 1, false, hb + 8, w8)                                                 \
    }

// QKV GEMM: M=4096 (b*2048+t), N=6144 (which*2048 + h*128 + d). grid 768 (32m x 24n).
__global__ __launch_bounds__(512) void k_gemm_qkv(
    const s16b* __restrict__ A, const s16b* __restrict__ Bt,
    s16b* __restrict__ Qb, s16b* __restrict__ Kb, s16b* __restrict__ Vt) {
    const int bid = blockIdx.x;
    const int sbid = (bid & 7) * 96 + (bid >> 3);
    const int bm = (sbid / 24) * 128, bn = (sbid % 24) * 256;
    GEMM8_MAINLOOP(A, Bt)
    const int mb = bm + wm * 64;
    const int nb = bn + wn * 64;
#pragma unroll
    for (int i = 0; i < 4; ++i) {
#pragma unroll
        for (int j = 0; j < 4; ++j) {
            int n = nb + j * 16 + r15;
            int which = n >> 11;
            int h = (n >> 7) & 15, d = n & 127;
            int m0 = mb + i * 16 + 4 * g;
            int b = m0 >> 11, t0 = m0 & 2047;
            size_t bh = (size_t)(b * 16 + h);
            if (which == 0) {
                size_t base = (bh * 2048 + t0) * 128 + d;
#pragma unroll
                for (int e = 0; e < 4; ++e) Qb[base + (size_t)e * 128] = f2bf(acc[i][j][e]);
            } else if (which == 1) {
                size_t base = (bh * 2048 + t0) * 128 + d;
#pragma unroll
                for (int e = 0; e < 4; ++e) Kb[base + (size_t)e * 128] = f2bf(acc[i][j][e]);
            } else {
                int pt = (t0 & ~31) + perm32(t0 & 31);   // t-permuted, 4-aligned
                size_t base = (bh * 128 + d) * 2048 + pt;
                bf16x4 pk;
#pragma unroll
                for (int e = 0; e < 4; ++e) pk[e] = f2bf(acc[i][j][e]);
                *(bf16x4*)(Vt + base) = pk;
            }
        }
    }
}

// Proj GEMM: M=4096, N=2048, fp32 out. grid 256 (32m x 8n).
__global__ __launch_bounds__(512) void k_gemm_proj(
    const s16b* __restrict__ A, const s16b* __restrict__ Bt, float* __restrict__ Co) {
    const int bid = blockIdx.x;
    const int sbid = (bid & 7) * 32 + (bid >> 3);
    const int bm = (sbid / 8) * 128, bn = (sbid % 8) * 256;
    GEMM8_MAINLOOP(A, Bt)
    const int mb = bm + wm * 64;
    const int nb = bn + wn * 64;
#pragma unroll
    for (int i = 0; i < 4; ++i) {
#pragma unroll
        for (int j = 0; j < 4; ++j) {
            int n = nb + j * 16 + r15;
            int m0 = mb + i * 16 + 4 * g;
#pragma unroll
            for (int e = 0; e < 4; ++e) Co[(size_t)(m0 + e) * 2048 + n] = acc[i][j][e];
        }
    }
}

// ---------------- RoPE: Q in place (plain); K -> Kp (d-permuted) ----------------
__global__ void k_rope(s16b* __restrict__ Qb, const s16b* __restrict__ Kb,
                       s16b* __restrict__ Kp,
                       const float* __restrict__ ctab, const float* __restrict__ stab) {
    int idx = blockIdx.x * 256 + threadIdx.x;   // 2*32*2048*16 = 2097152
    int i4 = idx & 15;
    int t = (idx >> 4) & 2047;
    int bh = (idx >> 15) & 31;
    int which = idx >> 20;
    int d = i4 * 4;                 // [0,64)
    const float* cp = ctab + t * 64 + d;
    const float* sp = stab + t * 64 + d;
    size_t rowoff = ((size_t)bh * 2048 + t) * 128;
    if (which == 0) {               // Q in place
        s16b* P = Qb + rowoff;
        bf16x4 a = *(bf16x4*)(P + d);
        bf16x4 bv = *(bf16x4*)(P + d + 64);
        bf16x4 ra, rb;
#pragma unroll
        for (int e = 0; e < 4; ++e) {
            float c = cp[e], s = sp[e];
            float x1 = bf2f(a[e]), x2 = bf2f(bv[e]);
            ra[e] = f2bf(x1 * c - x2 * s);
            rb[e] = f2bf(x2 * c + x1 * s);
        }
        *(bf16x4*)(P + d) = ra;
        *(bf16x4*)(P + d + 64) = rb;
    } else {                        // K: read plain, write permuted
        const s16b* Pi = Kb + rowoff;
        s16b* Po = Kp + rowoff;
        bf16x4 a = *(const bf16x4*)(Pi + d);
        bf16x4 bv = *(const bf16x4*)(Pi + d + 64);
        bf16x4 ra, rb;
#pragma unroll
        for (int e = 0; e < 4; ++e) {
            float c = cp[e], s = sp[e];
            float x1 = bf2f(a[e]), x2 = bf2f(bv[e]);
            ra[e] = f2bf(x1 * c - x2 * s);
            rb[e] = f2bf(x2 * c + x1 * s);
        }
        int d2 = d + 64;
        int pd  = (d  & ~31) + perm32(d  & 31);
        int pd2 = (d2 & ~31) + perm32(d2 & 31);
        *(bf16x4*)(Po + pd) = ra;
        *(bf16x4*)(Po + pd2) = rb;
    }
}

// ---------------- Flash attention (swapped QK^T, causal) ----------------
// grid (32 bh, 16 qtiles; qt = 15 - blockIdx.y so heavy blocks dispatch first).
__global__ __launch_bounds__(256) void k_attn(
    const s16b* __restrict__ Qb, const s16b* __restrict__ Kp,
    const s16b* __restrict__ Vt, s16b* __restrict__ AO) {
    __shared__ alignas(16) s16b Ks[64 * 128];   // [k][d-perm], 256B rows, 16 slots
    __shared__ alignas(16) s16b Vs[128 * 64];   // [d][t-perm], 128B rows, 8 slots
    const int tid = threadIdx.x;
    const int lane = tid & 63, wave = tid >> 6;
    const int g = lane >> 4, r15 = lane & 15;
    const int bh = blockIdx.x, qt = 15 - blockIdx.y;
    const int q0 = qt * 128 + wave * 32;
    const s16b* Qg = Qb + (size_t)bh * 2048 * 128;
    const char* Kg = (const char*)(Kp + (size_t)bh * 2048 * 128);
    const char* Vg = (const char*)(Vt + (size_t)bh * 128 * 2048);

    // hoist Q fragments (B-operand; global plain layout, 2x8B each)
    bf16x8 qf[2][4];
#pragma unroll
    for (int qs = 0; qs < 2; ++qs)
#pragma unroll
        for (int ds = 0; ds < 4; ++ds) {
            const s16b* p = Qg + (size_t)(q0 + qs * 16 + r15) * 128 + ds * 32 + 4 * g;
            bf16x4 lo = *(const bf16x4*)p;
            bf16x4 hi = *(const bf16x4*)(p + 16);
            qf[qs][ds] = __builtin_shufflevector(lo, hi, 0, 1, 2, 3, 4, 5, 6, 7);
        }

    f32x4 ot[8][2] = {};               // O^T accs: [dsub][qsub]
    float m_s[2] = {-3e38f, -3e38f};
    float l_s[2] = {0.f, 0.f};
    const float scale = 0.0883883476483184f;   // 1/sqrt(128)

    const int ktiles = qt * 2 + 2;
    for (int kt = 0; kt < ktiles; ++kt) {
        const int k0 = kt * 64;
        __syncthreads();
#pragma unroll
        for (int rr = 0; rr < 4; ++rr) {
            int uo = (rr * 256 + wave * 64) * 16;
            int o = uo + lane * 16;
            {   // K tile: 256B rows, 16 slots, swizzle low 3 slot bits
                int row = o >> 8, sl = (o >> 4) & 15;
                int sg = (sl ^ (row & 7)) << 4;
                gload_lds16(Kg + (size_t)(k0 + row) * 256 + sg, (char*)Ks + uo);
            }
            {   // V^T tile: 128B rows, 8 slots
                int row = o >> 7, sl = (o >> 4) & 7;
                int sg = (sl ^ (row & 7)) << 4;
                gload_lds16(Vg + (size_t)row * 4096 + (size_t)k0 * 2 + sg, (char*)Vs + uo);
            }
        }
        __syncthreads();

        if (k0 <= q0 + 31) {   // wave-uniform causal skip
            // S^T = K . Q^T   (rows = k, cols = q)
            f32x4 st[4][2] = {};
            __builtin_amdgcn_s_setprio(1);
#pragma unroll
            for (int ds = 0; ds < 4; ++ds) {
#pragma unroll
                for (int ks = 0; ks < 4; ++ks) {
                    bf16x8 kf = lds256(Ks, ks * 16 + r15, ds, g);
#pragma unroll
                    for (int qs = 0; qs < 2; ++qs)
                        st[ks][qs] = mfma16(kf, qf[qs][ds], st[ks][qs]);
                }
            }
            __builtin_amdgcn_s_setprio(0);
            // scale + causal mask
#pragma unroll
            for (int ks = 0; ks < 4; ++ks)
#pragma unroll
                for (int qs = 0; qs < 2; ++qs)
#pragma unroll
                    for (int e = 0; e < 4; ++e) {
                        int kk = k0 + ks * 16 + 4 * g + e;
                        int qq = q0 + qs * 16 + r15;
                        float s = st[ks][qs][e] * scale;
                        st[ks][qs][e] = (kk <= qq) ? s : -3e38f;
                    }
            // online softmax per q-column (lane-local + 2 shfl_xor)
            float sf[2];
#pragma unroll
            for (int qs = 0; qs < 2; ++qs) {
                float mx = -3e38f;
#pragma unroll
                for (int ks = 0; ks < 4; ++ks)
#pragma unroll
                    for (int e = 0; e < 4; ++e) mx = fmaxf(mx, st[ks][qs][e]);
                mx = fmaxf(mx, __shfl_xor(mx, 16));
                mx = fmaxf(mx, __shfl_xor(mx, 32));
                float mn = fmaxf(m_s[qs], mx);
                sf[qs] = __expf(m_s[qs] - mn);
                m_s[qs] = mn;
                float sum = 0.f;
#pragma unroll
                for (int ks = 0; ks < 4; ++ks)
#pragma unroll
                    for (int e = 0; e < 4; ++e) {
                        float p = __expf(st[ks][qs][e] - mn);
                        st[ks][qs][e] = p;
                        sum += p;
                    }
                sum += __shfl_xor(sum, 16);
                sum += __shfl_xor(sum, 32);
                l_s[qs] = l_s[qs] * sf[qs] + sum;
            }
            // P -> bf16 B-frags (register-only; C/D layout == B-operand layout)
            bf16x8 pb[2][2];
#pragma unroll
            for (int k2 = 0; k2 < 2; ++k2)
#pragma unroll
                for (int qs = 0; qs < 2; ++qs) {
                    bf16x8 f;
#pragma unroll
                    for (int jj = 0; jj < 8; ++jj)
                        f[jj] = f2bf(st[2 * k2 + (jj >> 2)][qs][jj & 3]);
                    pb[k2][qs] = f;
                }
            // rescale O
#pragma unroll
            for (int d8 = 0; d8 < 8; ++d8)
#pragma unroll
                for (int qs = 0; qs < 2; ++qs)
#pragma unroll
                    for (int e = 0; e < 4; ++e) ot[d8][qs][e] *= sf[qs];
            // O^T += V^T . P^T
            __builtin_amdgcn_s_setprio(1);
#pragma unroll
            for (int k2 = 0; k2 < 2; ++k2)
#pragma unroll
                for (int d8 = 0; d8 < 8; ++d8) {
                    bf16x8 vf = lds128(Vs, d8 * 16 + r15, k2, g);
#pragma unroll
                    for (int qs = 0; qs < 2; ++qs)
                        ot[d8][qs] = mfma16(vf, pb[k2][qs], ot[d8][qs]);
                }
            __builtin_amdgcn_s_setprio(0);
        }
    }
    // write AO [B,T,C] with C-permuted columns (proj GEMM A-operand layout)
    int b = bh >> 4, h = bh & 15;
#pragma unroll
    for (int qs = 0; qs < 2; ++qs) {
        float inv = 1.0f / l_s[qs];
        int q = q0 + qs * 16 + r15;
#pragma unroll
        for (int d8 = 0; d8 < 8; ++d8) {
            bf16x4 pk;
#pragma unroll
            for (int e = 0; e < 4; ++e) pk[e] = f2bf(ot[d8][qs][e] * inv);
            size_t off = ((size_t)(b * 2048 + q)) * 2048
                       + h * 128 + (d8 >> 1) * 32 + g * 8 + (d8 & 1) * 4;
            *(bf16x4*)(AO + off) = pk;
        }
    }
}

extern "C" void kernel_launch(void* const* d_in, const int* in_sizes, int n_in,
                              void* d_out, int out_size, void* d_ws, size_t ws_size,
                              hipStream_t stream) {
    const float* x = (const float*)d_in[0];
    const float* Wqkv = (const float*)d_in[1];
    const float* Wproj = (const float*)d_in[2];
    float* out = (float*)d_out;

    char* ws = (char*)d_ws;
    float* ctab = (float*)ws;
    float* stab = ctab + 2048 * 64;
    size_t off = 1048576;
    s16b* xb = (s16b*)(ws + off); off += 16777216;        // x bf16 K-perm; reused as AO
    s16b* wqkvt = (s16b*)(ws + off); off += 25165824;     // [6144][2048] bf16 K-perm; reused as Kp
    s16b* wprojt = (s16b*)(ws + off); off += 8388608;     // [2048][2048] bf16 K-perm
    s16b* Qb = (s16b*)(ws + off); off += 16777216;        // [2,16,2048,128] plain
    s16b* Kb = (s16b*)(ws + off); off += 16777216;        // plain (pre-RoPE)
    s16b* Vt = (s16b*)(ws + off); off += 16777216;        // [2,16,128,2048] t-perm
    s16b* AO = xb;      // alias: xb dead after QKV GEMM
    s16b* Kp = wqkvt;   // alias: wqkvt dead after QKV GEMM (RoPE'd K, d-perm)

    k_tables<<<dim3(512), dim3(256), 0, stream>>>(ctab, stab);
    k_cvt_x<<<dim3(8192), dim3(256), 0, stream>>>(x, xb);
    k_tcvt<<<dim3(192, 64), dim3(256), 0, stream>>>(Wqkv, wqkvt, 2048, 6144);
    k_tcvt<<<dim3(64, 64), dim3(256), 0, stream>>>(Wproj, wprojt, 2048, 2048);
    k_gemm_qkv<<<dim3(768), dim3(512), 0, stream>>>(xb, wqkvt, Qb, Kb, Vt);
    k_rope<<<dim3(8192), dim3(256), 0, stream>>>(Qb, Kb, Kp, ctab, stab);
    k_attn<<<dim3(32, 16), dim3(256), 0, stream>>>(Qb, Kp, Vt, AO);
    k_gemm_proj<<<dim3(256), dim3(512), 0, stream>>>(AO, wprojt, out);
}

// Round 4
// 277.055 us; speedup vs baseline: 1.7722x; 1.0602x over previous
//
#include <hip/hip_runtime.h>
#include <hip/hip_bf16.h>

typedef short s16b;
using bf16x4 = __attribute__((ext_vector_type(4))) short;
using bf16x8 = __attribute__((ext_vector_type(8))) short;
using f32x4  = __attribute__((ext_vector_type(4))) float;

#define DEVINL __device__ __forceinline__

DEVINL float bf2f(short u) {
    union { float f; unsigned u; } x;
    x.u = ((unsigned)(unsigned short)u) << 16;
    return x.f;
}
DEVINL short f2bf(float f) {   // round-to-nearest-even
    unsigned u = __builtin_bit_cast(unsigned, f);
    u += 0x7FFFu + ((u >> 16) & 1u);
    return (short)(u >> 16);
}

DEVINL f32x4 mfma16(bf16x8 a, bf16x8 b, f32x4 c) {
    return __builtin_amdgcn_mfma_f32_16x16x32_bf16(a, b, c, 0, 0, 0);
}

DEVINL void gload_lds16(const void* g, void* lds_uniform) {
    __builtin_amdgcn_global_load_lds(
        (const __attribute__((address_space(1))) char*)(const char*)g,
        (__attribute__((address_space(3))) char*)(char*)lds_uniform, 16, 0, 0);
}

// stored position of k within a 32-element K-group:
// chunk order [0-3,16-19,4-7,20-23,8-11,24-27,12-15,28-31]
DEVINL int perm32(int k) {
    return ((k >> 2) & 3) * 8 + ((k >> 4) & 1) * 4 + (k & 3);
}

// LDS frag read, 128B rows, 8 slots of 16B, swizzle slot^=(row&7). (attn kernel)
DEVINL bf16x8 lds128(const s16b* base, int row, int ks, int g) {
    const char* p = (const char*)base + row * 128 + ((((ks << 2) + g) ^ (row & 7)) << 4);
    return *(const bf16x8*)p;
}
// LDS frag read, 256B rows, 16 slots, swizzle low 3 slot bits.
DEVINL bf16x8 lds256(const s16b* base, int row, int ds, int g) {
    const char* p = (const char*)base + row * 256 + ((((ds << 2) + g) ^ (row & 7)) << 4);
    return *(const bf16x8*)p;
}

// ---------------- RoPE tables: cos/sin [2048][64] fp32 ----------------
__global__ void k_tables(float* __restrict__ ctab, float* __restrict__ stab) {
    int idx = blockIdx.x * 256 + threadIdx.x;      // 2048*64 = 131072
    int i = idx & 63, t = idx >> 6;
    float inv = powf(10000.0f, -(float)i * (1.0f / 64.0f));
    float fr = (float)t * inv;
    ctab[idx] = cosf(fr);
    stab[idx] = sinf(fr);
}

// ---------------- x fp32 -> bf16, K-permuted rows ----------------
__global__ void k_cvt_x(const float* __restrict__ x, s16b* __restrict__ xb) {
    int idx = blockIdx.x * 256 + threadIdx.x;        // 2097152 threads, 4 elems each
    int p = idx * 4;                                  // stored position
    int row = p >> 11, pc = p & 2047;
    int grp = pc >> 5, sp = pc & 31;
    int c = sp >> 3, half = (sp >> 2) & 1;
    int ksrc = grp * 32 + half * 16 + c * 4;          // source k (4 contiguous)
    float4 v = *(const float4*)(x + (size_t)row * 2048 + ksrc);
    bf16x4 o;
    o[0] = f2bf(v.x); o[1] = f2bf(v.y); o[2] = f2bf(v.z); o[3] = f2bf(v.w);
    *(bf16x4*)(xb + (size_t)row * 2048 + pc) = o;
}

// ---------------- W [R][C] fp32 -> Wt [C][R] bf16, K(=R)-permuted ----------------
__global__ void k_tcvt(const float* __restrict__ in, s16b* __restrict__ out, int R, int C) {
    __shared__ float tile[32][33];
    int tx = threadIdx.x & 31, ty = threadIdx.x >> 5;   // 32 x 8
    int c0 = blockIdx.x * 32, r0 = blockIdx.y * 32;     // r0 multiple of 32
#pragma unroll
    for (int kk = 0; kk < 4; ++kk) {
        int r = ty + kk * 8;
        tile[r][tx] = in[(size_t)(r0 + r) * C + c0 + tx];
    }
    __syncthreads();
#pragma unroll
    for (int kk = 0; kk < 4; ++kk) {
        int r = ty + kk * 8;
        out[(size_t)(c0 + r) * R + r0 + perm32(tx)] = f2bf(tile[tx][r]);
    }
}

// ================ 8-phase GEMM: BM=128, BN=256, BK=64, 8 waves ================
// A [M][2048] K-perm, Bt [N][2048] K-perm. LDS 96KB:
//   A bufs: 16KB each at 0 / 16384       (128 rows x 128B, 8-slot XOR row&7)
//   B bufs: 32KB each at 32768 / 65536   (256 rows x 128B, same swizzle)
// Halves: A0/A1 = 64 rows (1 load/thread), B0/B1 = 128 rows (2 loads).
// Per K-tile (4 phases, staging tile tau+1): p0:B0 p1:A0 p2:A1 p3:B1.
// Per-wave FIFO: entering p0 outstanding = B1(tau)[2].
//   p0 +B0'(2)->4, vmcnt(2) retires B1(tau)   [p1 reads B1(tau)]
//   p1 +A0'(1)->3 ; p2 +A1'(1)->4
//   p3 +B1'(2)->6, vmcnt(2) retires B0',A0',A1'  [next p0 reads them]
// lgkmcnt(0) BEFORE the single per-phase barrier => no outstanding ds_reads
// cross a barrier (WAR-safe: staging always targets the opposite buffer).
#define STG_A(H, KB, DB)                                                       \
  gload_lds16(srcA + (H) * 262144 + (KB), lds + (DB) * 16384 + (H) * 8192 + wave * 1024);
#define STG_B(H, KB, DB)                                                       \
  gload_lds16(srcB + (H) * 524288 + (KB),                                      \
              lds + 32768 + (DB) * 32768 + (H) * 16384 + wave * 1024);         \
  gload_lds16(srcB + (H) * 524288 + 262144 + (KB),                             \
              lds + 32768 + (DB) * 32768 + (H) * 16384 + 8192 + wave * 1024);

#define AF_READ(BUF, KS)                                                       \
    _Pragma("unroll")                                                          \
    for (int fi = 0; fi < 4; ++fi) {                                           \
      int row = (fi >> 1) * 64 + wm * 32 + (fi & 1) * 16 + r15;                \
      af[fi] = *(const bf16x8*)(lds + (BUF) * 16384 + row * 128                \
               + ((((KS) * 4 + g) ^ (row & 7)) << 4));                         \
    }
#define BF_READ(BUF, KS, BH)                                                   \
    _Pragma("unroll")                                                          \
    for (int fj = 0; fj < 2; ++fj) {                                           \
      int row = (BH) * 128 + wn * 32 + fj * 16 + r15;                          \
      bfr[fj] = *(const bf16x8*)(lds + 32768 + (BUF) * 32768 + row * 128       \
                + ((((KS) * 4 + g) ^ (row & 7)) << 4));                        \
    }

#define PH(BUF, KS, BH, NEWA, STGC, WAITN)                                     \
  {                                                                            \
    if (NEWA) AF_READ(BUF, KS)                                                 \
    BF_READ(BUF, KS, BH)                                                       \
    STGC                                                                       \
    if ((WAITN) == 2) { asm volatile("s_waitcnt vmcnt(2)" ::: "memory");       \
                        __builtin_amdgcn_sched_barrier(0); }                   \
    else if ((WAITN) == 0) { asm volatile("s_waitcnt vmcnt(0)" ::: "memory");  \
                        __builtin_amdgcn_sched_barrier(0); }                   \
    asm volatile("s_waitcnt lgkmcnt(0)" ::: "memory");                         \
    __builtin_amdgcn_sched_barrier(0);                                         \
    __builtin_amdgcn_s_barrier();                                              \
    __builtin_amdgcn_sched_barrier(0);                                         \
    __builtin_amdgcn_s_setprio(1);                                             \
    _Pragma("unroll")                                                          \
    for (int fi = 0; fi < 4; ++fi)                                             \
      _Pragma("unroll")                                                        \
      for (int fj = 0; fj < 2; ++fj)                                           \
        acc[fi][(BH) * 2 + fj] = mfma16(af[fi], bfr[fj], acc[fi][(BH) * 2 + fj]); \
    __builtin_amdgcn_s_setprio(0);                                             \
  }

#define GEMM8_MAINLOOP(A_, B_)                                                 \
    __shared__ __attribute__((aligned(16))) char lds[98304];                   \
    const int tid = threadIdx.x;                                               \
    const int lane = tid & 63, wave = tid >> 6;                                \
    const int g = lane >> 4, r15 = lane & 15;                                  \
    const int wm = wave >> 2, wn = wave & 3;                                   \
    const int lin = wave * 1024 + (lane << 4);                                 \
    const int rowL = lin >> 7;                                                 \
    const int swzL = ((((lin >> 4) & 7) ^ (rowL & 7)) << 4);                   \
    const char* srcA = (const char*)(A_) + (size_t)(bm + rowL) * 4096 + swzL;  \
    const char* srcB = (const char*)(B_) + (size_t)(bn + rowL) * 4096 + swzL;  \
    f32x4 acc[4][4] = {};                                                      \
    bf16x8 af[4], bfr[2];                                                      \
    STG_B(0, 0, 0) STG_A(0, 0, 0) STG_A(1, 0, 0) STG_B(1, 0, 0)                \
    asm volatile("s_waitcnt vmcnt(2)" ::: "memory");                           \
    __builtin_amdgcn_sched_barrier(0);                                         \
    __builtin_amdgcn_s_barrier();                                              \
    for (int t2 = 0; t2 < 15; ++t2) {                                          \
        const int kb1 = t2 * 256 + 128, kb2 = t2 * 256 + 256;                  \
        PH(0, 0, 0, 1, STG_B(0, kb1, 1), 2)                                    \
        PH(0, 0, 1, 0, STG_A(0, kb1, 1), -1)                                   \
        PH(0, 1, 0, 1, STG_A(1, kb1, 1), -1)                                   \
        PH(0, 1, 1, 0, STG_B(1, kb1, 1), 2)                                    \
        PH(1, 0, 0, 1, STG_B(0, kb2, 0), 2)                                    \
        PH(1, 0, 1, 0, STG_A(0, kb2, 0), -1)                                   \
        PH(1, 1, 0, 1, STG_A(1, kb2, 0), -1)                                   \
        PH(1, 1, 1, 0, STG_B(1, kb2, 0), 2)                                    \
    }                                                                          \
    PH(0, 0, 0, 1, STG_B(0, 3968, 1), 2)                                       \
    PH(0, 0, 1, 0, STG_A(0, 3968, 1), -1)                                      \
    PH(0, 1, 0, 1, STG_A(1, 3968, 1), -1)                                      \
    PH(0, 1, 1, 0, STG_B(1, 3968, 1), 2)                                       \
    PH(1, 0, 0, 1, , 0)                                                        \
    PH(1, 0, 1, 0, , -1)                                                       \
    PH(1, 1, 0, 1, , -1)                                                       \
    PH(1, 1, 1, 0, , -1)

// QKV GEMM: M=4096 (b*2048+t), N=6144 (which*2048 + h*128 + d). grid 768.
__global__ __launch_bounds__(512) void k_gemm_qkv(
    const s16b* __restrict__ A, const s16b* __restrict__ Bt,
    s16b* __restrict__ Qb, s16b* __restrict__ Kb, s16b* __restrict__ Vt) {
    const int bid = blockIdx.x;
    const int sbid = (bid & 7) * 96 + (bid >> 3);
    const int bm = (sbid / 24) * 128, bn = (sbid % 24) * 256;
    GEMM8_MAINLOOP(A, Bt)
#pragma unroll
    for (int i = 0; i < 4; ++i) {
        int m0 = bm + (i >> 1) * 64 + wm * 32 + (i & 1) * 16 + 4 * g;
        int b = m0 >> 11, t0 = m0 & 2047;
#pragma unroll
        for (int j = 0; j < 4; ++j) {
            int n = bn + (j >> 1) * 128 + wn * 32 + (j & 1) * 16 + r15;
            int which = n >> 11;
            int h = (n >> 7) & 15, d = n & 127;
            size_t bh = (size_t)(b * 16 + h);
            if (which == 0) {
                size_t base = (bh * 2048 + t0) * 128 + d;
#pragma unroll
                for (int e = 0; e < 4; ++e) Qb[base + (size_t)e * 128] = f2bf(acc[i][j][e]);
            } else if (which == 1) {
                size_t base = (bh * 2048 + t0) * 128 + d;
#pragma unroll
                for (int e = 0; e < 4; ++e) Kb[base + (size_t)e * 128] = f2bf(acc[i][j][e]);
            } else {
                int pt = (t0 & ~31) + perm32(t0 & 31);   // t-permuted, 4-aligned
                size_t base = (bh * 128 + d) * 2048 + pt;
                bf16x4 pk;
#pragma unroll
                for (int e = 0; e < 4; ++e) pk[e] = f2bf(acc[i][j][e]);
                *(bf16x4*)(Vt + base) = pk;
            }
        }
    }
}

// Proj GEMM: M=4096, N=2048, fp32 out. grid 256.
__global__ __launch_bounds__(512) void k_gemm_proj(
    const s16b* __restrict__ A, const s16b* __restrict__ Bt, float* __restrict__ Co) {
    const int bid = blockIdx.x;
    const int sbid = (bid & 7) * 32 + (bid >> 3);
    const int bm = (sbid / 8) * 128, bn = (sbid % 8) * 256;
    GEMM8_MAINLOOP(A, Bt)
#pragma unroll
    for (int i = 0; i < 4; ++i) {
        int m0 = bm + (i >> 1) * 64 + wm * 32 + (i & 1) * 16 + 4 * g;
#pragma unroll
        for (int j = 0; j < 4; ++j) {
            int n = bn + (j >> 1) * 128 + wn * 32 + (j & 1) * 16 + r15;
#pragma unroll
            for (int e = 0; e < 4; ++e) Co[(size_t)(m0 + e) * 2048 + n] = acc[i][j][e];
        }
    }
}

// ---------------- RoPE: Q in place (plain); K -> Kp (d-permuted) ----------------
__global__ void k_rope(s16b* __restrict__ Qb, const s16b* __restrict__ Kb,
                       s16b* __restrict__ Kp,
                       const float* __restrict__ ctab, const float* __restrict__ stab) {
    int idx = blockIdx.x * 256 + threadIdx.x;   // 2*32*2048*16 = 2097152
    int i4 = idx & 15;
    int t = (idx >> 4) & 2047;
    int bh = (idx >> 15) & 31;
    int which = idx >> 20;
    int d = i4 * 4;                 // [0,64)
    const float* cp = ctab + t * 64 + d;
    const float* sp = stab + t * 64 + d;
    size_t rowoff = ((size_t)bh * 2048 + t) * 128;
    if (which == 0) {               // Q in place
        s16b* P = Qb + rowoff;
        bf16x4 a = *(bf16x4*)(P + d);
        bf16x4 bv = *(bf16x4*)(P + d + 64);
        bf16x4 ra, rb;
#pragma unroll
        for (int e = 0; e < 4; ++e) {
            float c = cp[e], s = sp[e];
            float x1 = bf2f(a[e]), x2 = bf2f(bv[e]);
            ra[e] = f2bf(x1 * c - x2 * s);
            rb[e] = f2bf(x2 * c + x1 * s);
        }
        *(bf16x4*)(P + d) = ra;
        *(bf16x4*)(P + d + 64) = rb;
    } else {                        // K: read plain, write permuted
        const s16b* Pi = Kb + rowoff;
        s16b* Po = Kp + rowoff;
        bf16x4 a = *(const bf16x4*)(Pi + d);
        bf16x4 bv = *(const bf16x4*)(Pi + d + 64);
        bf16x4 ra, rb;
#pragma unroll
        for (int e = 0; e < 4; ++e) {
            float c = cp[e], s = sp[e];
            float x1 = bf2f(a[e]), x2 = bf2f(bv[e]);
            ra[e] = f2bf(x1 * c - x2 * s);
            rb[e] = f2bf(x2 * c + x1 * s);
        }
        int d2 = d + 64;
        int pd  = (d  & ~31) + perm32(d  & 31);
        int pd2 = (d2 & ~31) + perm32(d2 & 31);
        *(bf16x4*)(Po + pd) = ra;
        *(bf16x4*)(Po + pd2) = rb;
    }
}

// ---------------- Flash attention (swapped QK^T, causal) ----------------
// grid (32 bh, 16 qtiles; qt = 15 - blockIdx.y so heavy blocks dispatch first).
__global__ __launch_bounds__(256) void k_attn(
    const s16b* __restrict__ Qb, const s16b* __restrict__ Kp,
    const s16b* __restrict__ Vt, s16b* __restrict__ AO) {
    __shared__ alignas(16) s16b Ks[64 * 128];   // [k][d-perm], 256B rows, 16 slots
    __shared__ alignas(16) s16b Vs[128 * 64];   // [d][t-perm], 128B rows, 8 slots
    const int tid = threadIdx.x;
    const int lane = tid & 63, wave = tid >> 6;
    const int g = lane >> 4, r15 = lane & 15;
    const int bh = blockIdx.x, qt = 15 - blockIdx.y;
    const int q0 = qt * 128 + wave * 32;
    const s16b* Qg = Qb + (size_t)bh * 2048 * 128;
    const char* Kg = (const char*)(Kp + (size_t)bh * 2048 * 128);
    const char* Vg = (const char*)(Vt + (size_t)bh * 128 * 2048);

    // hoist Q fragments (B-operand; global plain layout, 2x8B each)
    bf16x8 qf[2][4];
#pragma unroll
    for (int qs = 0; qs < 2; ++qs)
#pragma unroll
        for (int ds = 0; ds < 4; ++ds) {
            const s16b* p = Qg + (size_t)(q0 + qs * 16 + r15) * 128 + ds * 32 + 4 * g;
            bf16x4 lo = *(const bf16x4*)p;
            bf16x4 hi = *(const bf16x4*)(p + 16);
            qf[qs][ds] = __builtin_shufflevector(lo, hi, 0, 1, 2, 3, 4, 5, 6, 7);
        }

    f32x4 ot[8][2] = {};               // O^T accs: [dsub][qsub]
    float m_s[2] = {-3e38f, -3e38f};
    float l_s[2] = {0.f, 0.f};
    const float scale = 0.0883883476483184f;   // 1/sqrt(128)

    const int ktiles = qt * 2 + 2;
    for (int kt = 0; kt < ktiles; ++kt) {
        const int k0 = kt * 64;
        __syncthreads();
#pragma unroll
        for (int rr = 0; rr < 4; ++rr) {
            int uo = (rr * 256 + wave * 64) * 16;
            int o = uo + lane * 16;
            {   // K tile: 256B rows, 16 slots, swizzle low 3 slot bits
                int row = o >> 8, sl = (o >> 4) & 15;
                int sg = (sl ^ (row & 7)) << 4;
                gload_lds16(Kg + (size_t)(k0 + row) * 256 + sg, (char*)Ks + uo);
            }
            {   // V^T tile: 128B rows, 8 slots
                int row = o >> 7, sl = (o >> 4) & 7;
                int sg = (sl ^ (row & 7)) << 4;
                gload_lds16(Vg + (size_t)row * 4096 + (size_t)k0 * 2 + sg, (char*)Vs + uo);
            }
        }
        __syncthreads();

        if (k0 <= q0 + 31) {   // wave-uniform causal skip
            // S^T = K . Q^T   (rows = k, cols = q)
            f32x4 st[4][2] = {};
            __builtin_amdgcn_s_setprio(1);
#pragma unroll
            for (int ds = 0; ds < 4; ++ds) {
#pragma unroll
                for (int ks = 0; ks < 4; ++ks) {
                    bf16x8 kf = lds256(Ks, ks * 16 + r15, ds, g);
#pragma unroll
                    for (int qs = 0; qs < 2; ++qs)
                        st[ks][qs] = mfma16(kf, qf[qs][ds], st[ks][qs]);
                }
            }
            __builtin_amdgcn_s_setprio(0);
            // scale + causal mask
#pragma unroll
            for (int ks = 0; ks < 4; ++ks)
#pragma unroll
                for (int qs = 0; qs < 2; ++qs)
#pragma unroll
                    for (int e = 0; e < 4; ++e) {
                        int kk = k0 + ks * 16 + 4 * g + e;
                        int qq = q0 + qs * 16 + r15;
                        float s = st[ks][qs][e] * scale;
                        st[ks][qs][e] = (kk <= qq) ? s : -3e38f;
                    }
            // online softmax per q-column (lane-local + 2 shfl_xor)
            float sf[2];
#pragma unroll
            for (int qs = 0; qs < 2; ++qs) {
                float mx = -3e38f;
#pragma unroll
                for (int ks = 0; ks < 4; ++ks)
#pragma unroll
                    for (int e = 0; e < 4; ++e) mx = fmaxf(mx, st[ks][qs][e]);
                mx = fmaxf(mx, __shfl_xor(mx, 16));
                mx = fmaxf(mx, __shfl_xor(mx, 32));
                float mn = fmaxf(m_s[qs], mx);
                sf[qs] = __expf(m_s[qs] - mn);
                m_s[qs] = mn;
                float sum = 0.f;
#pragma unroll
                for (int ks = 0; ks < 4; ++ks)
#pragma unroll
                    for (int e = 0; e < 4; ++e) {
                        float p = __expf(st[ks][qs][e] - mn);
                        st[ks][qs][e] = p;
                        sum += p;
                    }
                sum += __shfl_xor(sum, 16);
                sum += __shfl_xor(sum, 32);
                l_s[qs] = l_s[qs] * sf[qs] + sum;
            }
            // P -> bf16 B-frags (register-only; C/D layout == B-operand layout)
            bf16x8 pb[2][2];
#pragma unroll
            for (int k2 = 0; k2 < 2; ++k2)
#pragma unroll
                for (int qs = 0; qs < 2; ++qs) {
                    bf16x8 f;
#pragma unroll
                    for (int jj = 0; jj < 8; ++jj)
                        f[jj] = f2bf(st[2 * k2 + (jj >> 2)][qs][jj & 3]);
                    pb[k2][qs] = f;
                }
            // rescale O
#pragma unroll
            for (int d8 = 0; d8 < 8; ++d8)
#pragma unroll
                for (int qs = 0; qs < 2; ++qs)
#pragma unroll
                    for (int e = 0; e < 4; ++e) ot[d8][qs][e] *= sf[qs];
            // O^T += V^T . P^T
            __builtin_amdgcn_s_setprio(1);
#pragma unroll
            for (int k2 = 0; k2 < 2; ++k2)
#pragma unroll
                for (int d8 = 0; d8 < 8; ++d8) {
                    bf16x8 vf = lds128(Vs, d8 * 16 + r15, k2, g);
#pragma unroll
                    for (int qs = 0; qs < 2; ++qs)
                        ot[d8][qs] = mfma16(vf, pb[k2][qs], ot[d8][qs]);
                }
            __builtin_amdgcn_s_setprio(0);
        }
    }
    // write AO [B,T,C] with C-permuted columns (proj GEMM A-operand layout)
    int b = bh >> 4, h = bh & 15;
#pragma unroll
    for (int qs = 0; qs < 2; ++qs) {
        float inv = 1.0f / l_s[qs];
        int q = q0 + qs * 16 + r15;
#pragma unroll
        for (int d8 = 0; d8 < 8; ++d8) {
            bf16x4 pk;
#pragma unroll
            for (int e = 0; e < 4; ++e) pk[e] = f2bf(ot[d8][qs][e] * inv);
            size_t off = ((size_t)(b * 2048 + q)) * 2048
                       + h * 128 + (d8 >> 1) * 32 + g * 8 + (d8 & 1) * 4;
            *(bf16x4*)(AO + off) = pk;
        }
    }
}

extern "C" void kernel_launch(void* const* d_in, const int* in_sizes, int n_in,
                              void* d_out, int out_size, void* d_ws, size_t ws_size,
                              hipStream_t stream) {
    const float* x = (const float*)d_in[0];
    const float* Wqkv = (const float*)d_in[1];
    const float* Wproj = (const float*)d_in[2];
    float* out = (float*)d_out;

    char* ws = (char*)d_ws;
    float* ctab = (float*)ws;
    float* stab = ctab + 2048 * 64;
    size_t off = 1048576;
    s16b* xb = (s16b*)(ws + off); off += 16777216;        // x bf16 K-perm; reused as AO
    s16b* wqkvt = (s16b*)(ws + off); off += 25165824;     // [6144][2048] bf16 K-perm; reused as Kp
    s16b* wprojt = (s16b*)(ws + off); off += 8388608;     // [2048][2048] bf16 K-perm
    s16b* Qb = (s16b*)(ws + off); off += 16777216;        // [2,16,2048,128] plain
    s16b* Kb = (s16b*)(ws + off); off += 16777216;        // plain (pre-RoPE)
    s16b* Vt = (s16b*)(ws + off); off += 16777216;        // [2,16,128,2048] t-perm
    s16b* AO = xb;      // alias: xb dead after QKV GEMM
    s16b* Kp = wqkvt;   // alias: wqkvt dead after QKV GEMM (RoPE'd K, d-perm)

    k_tables<<<dim3(512), dim3(256), 0, stream>>>(ctab, stab);
    k_cvt_x<<<dim3(8192), dim3(256), 0, stream>>>(x, xb);
    k_tcvt<<<dim3(192, 64), dim3(256), 0, stream>>>(Wqkv, wqkvt, 2048, 6144);
    k_tcvt<<<dim3(64, 64), dim3(256), 0, stream>>>(Wproj, wprojt, 2048, 2048);
    k_gemm_qkv<<<dim3(768), dim3(512), 0, stream>>>(xb, wqkvt, Qb, Kb, Vt);
    k_rope<<<dim3(8192), dim3(256), 0, stream>>>(Qb, Kb, Kp, ctab, stab);
    k_attn<<<dim3(32, 16), dim3(256), 0, stream>>>(Qb, Kp, Vt, AO);
    k_gemm_proj<<<dim3(256), dim3(512), 0, stream>>>(AO, wprojt, out);
}

// Round 5
// 273.054 us; speedup vs baseline: 1.7982x; 1.0147x over previous
//
#include <hip/hip_runtime.h>
#include <hip/hip_bf16.h>

typedef short s16b;
using bf16x4 = __attribute__((ext_vector_type(4))) short;
using bf16x8 = __attribute__((ext_vector_type(8))) short;
using f32x4  = __attribute__((ext_vector_type(4))) float;

#define DEVINL __device__ __forceinline__

DEVINL float bf2f(short u) {
    union { float f; unsigned u; } x;
    x.u = ((unsigned)(unsigned short)u) << 16;
    return x.f;
}
DEVINL short f2bf(float f) {   // round-to-nearest-even
    unsigned u = __builtin_bit_cast(unsigned, f);
    u += 0x7FFFu + ((u >> 16) & 1u);
    return (short)(u >> 16);
}

DEVINL f32x4 mfma16(bf16x8 a, bf16x8 b, f32x4 c) {
    return __builtin_amdgcn_mfma_f32_16x16x32_bf16(a, b, c, 0, 0, 0);
}

DEVINL void gload_lds16(const void* g, void* lds_uniform) {
    __builtin_amdgcn_global_load_lds(
        (const __attribute__((address_space(1))) char*)(const char*)g,
        (__attribute__((address_space(3))) char*)(char*)lds_uniform, 16, 0, 0);
}

// stored position of k within a 32-element K-group:
// chunk order [0-3,16-19,4-7,20-23,8-11,24-27,12-15,28-31]
DEVINL int perm32(int k) {
    return ((k >> 2) & 3) * 8 + ((k >> 4) & 1) * 4 + (k & 3);
}

// LDS frag read, 128B rows, 8 slots of 16B, swizzle slot^=(row&7). (attn kernel)
DEVINL bf16x8 lds128(const s16b* base, int row, int ks, int g) {
    const char* p = (const char*)base + row * 128 + ((((ks << 2) + g) ^ (row & 7)) << 4);
    return *(const bf16x8*)p;
}
// LDS frag read, 256B rows, 16 slots, swizzle low 3 slot bits.
DEVINL bf16x8 lds256(const s16b* base, int row, int ds, int g) {
    const char* p = (const char*)base + row * 256 + ((((ds << 2) + g) ^ (row & 7)) << 4);
    return *(const bf16x8*)p;
}

// ---------------- RoPE tables: cos/sin [2048][64] fp32 ----------------
__global__ void k_tables(float* __restrict__ ctab, float* __restrict__ stab) {
    int idx = blockIdx.x * 256 + threadIdx.x;      // 2048*64 = 131072
    int i = idx & 63, t = idx >> 6;
    float inv = powf(10000.0f, -(float)i * (1.0f / 64.0f));
    float fr = (float)t * inv;
    ctab[idx] = cosf(fr);
    stab[idx] = sinf(fr);
}

// ---------------- x fp32 -> bf16, K-permuted rows ----------------
__global__ void k_cvt_x(const float* __restrict__ x, s16b* __restrict__ xb) {
    int idx = blockIdx.x * 256 + threadIdx.x;        // 2097152 threads, 4 elems each
    int p = idx * 4;                                  // stored position
    int row = p >> 11, pc = p & 2047;
    int grp = pc >> 5, sp = pc & 31;
    int c = sp >> 3, half = (sp >> 2) & 1;
    int ksrc = grp * 32 + half * 16 + c * 4;          // source k (4 contiguous)
    float4 v = *(const float4*)(x + (size_t)row * 2048 + ksrc);
    bf16x4 o;
    o[0] = f2bf(v.x); o[1] = f2bf(v.y); o[2] = f2bf(v.z); o[3] = f2bf(v.w);
    *(bf16x4*)(xb + (size_t)row * 2048 + pc) = o;
}

// ---------------- W [R][C] fp32 -> Wt [C][R] bf16, K(=R)-permuted ----------------
__global__ void k_tcvt(const float* __restrict__ in, s16b* __restrict__ out, int R, int C) {
    __shared__ float tile[32][33];
    int tx = threadIdx.x & 31, ty = threadIdx.x >> 5;   // 32 x 8
    int c0 = blockIdx.x * 32, r0 = blockIdx.y * 32;     // r0 multiple of 32
#pragma unroll
    for (int kk = 0; kk < 4; ++kk) {
        int r = ty + kk * 8;
        tile[r][tx] = in[(size_t)(r0 + r) * C + c0 + tx];
    }
    __syncthreads();
#pragma unroll
    for (int kk = 0; kk < 4; ++kk) {
        int r = ty + kk * 8;
        out[(size_t)(c0 + r) * R + r0 + perm32(tx)] = f2bf(tile[tx][r]);
    }
}

// ======= Triple-buffered deep-pipeline GEMM: BM=128, BN=256, BK=64, 8 waves =======
// A [M][2048] K-perm, Bt [N][2048] K-perm. LDS 144KB:
//   A bufs (16KB): 0 / 16384 / 32768          (128 rows x 128B, 8-slot XOR row&7)
//   B bufs (32KB): 49152 / 81920 / 114688     (256 rows x 128B, same swizzle)
// Tile tau lives in buf tau%3. During tile tau's phase 0 we stage tile tau+2
// into buf (tau+2)%3 (its last reads finished at tile tau-1 -> WAR-safe with
// one barrier per tile limiting wave drift to <1 tile).
// Per-wave FIFO: entering tile tau: outstanding = tau+1's 6 loads;
//   p0 issues tau+2's 6 -> 12; p1: vmcnt(6) retires tau+1's 6 (needed after
//   this tile's barrier), leaving tau+2's 6 in flight across 4 phases.
#define STG_TILE(DB, KB)                                                       \
  gload_lds16(srcA + (KB), lds + (DB) * 16384 + tid16);                        \
  gload_lds16(srcA + 262144 + (KB), lds + (DB) * 16384 + 8192 + tid16);        \
  gload_lds16(srcB + (KB), lds + 49152 + (DB) * 32768 + tid16);                \
  gload_lds16(srcB + 262144 + (KB), lds + 49152 + (DB) * 32768 + 8192 + tid16);\
  gload_lds16(srcB + 524288 + (KB), lds + 49152 + (DB) * 32768 + 16384 + tid16);\
  gload_lds16(srcB + 786432 + (KB), lds + 49152 + (DB) * 32768 + 24576 + tid16);

#define AF_READ(B, KS)                                                         \
    _Pragma("unroll")                                                          \
    for (int fi = 0; fi < 4; ++fi) {                                           \
      int row = (fi >> 1) * 64 + wm * 32 + (fi & 1) * 16 + r15;                \
      af[fi] = *(const bf16x8*)(lds + (B) * 16384 + row * 128                  \
               + ((((KS) * 4 + g) ^ (row & 7)) << 4));                         \
    }
#define BF_READ(B, KS)                                                         \
    _Pragma("unroll")                                                          \
    for (int fj = 0; fj < 4; ++fj) {                                           \
      int row = (fj >> 1) * 128 + wn * 32 + (fj & 1) * 16 + r15;               \
      bfr[fj] = *(const bf16x8*)(lds + 49152 + (B) * 32768 + row * 128         \
                + ((((KS) * 4 + g) ^ (row & 7)) << 4));                        \
    }

#define MFMAS                                                                  \
  __builtin_amdgcn_s_setprio(1);                                               \
  _Pragma("unroll")                                                            \
  for (int fi = 0; fi < 4; ++fi)                                               \
    _Pragma("unroll")                                                          \
    for (int fj = 0; fj < 4; ++fj)                                             \
      acc[fi][fj] = mfma16(af[fi], bfr[fj], acc[fi][fj]);                      \
  __builtin_amdgcn_s_setprio(0);

#define DO_TILE(B, B2, KB, DOSTG, WN)                                          \
  {                                                                            \
    AF_READ(B, 0) BF_READ(B, 0)                                                \
    if (DOSTG) { STG_TILE(B2, (KB) + 256) }                                    \
    MFMAS                                                                      \
    AF_READ(B, 1) BF_READ(B, 1)                                                \
    if ((WN) == 6) { asm volatile("s_waitcnt vmcnt(6)" ::: "memory");          \
                     __builtin_amdgcn_sched_barrier(0); }                      \
    else if ((WN) == 0) { asm volatile("s_waitcnt vmcnt(0)" ::: "memory");     \
                     __builtin_amdgcn_sched_barrier(0); }                      \
    MFMAS                                                                      \
    __builtin_amdgcn_s_barrier();                                              \
    asm volatile("" ::: "memory");                                             \
    __builtin_amdgcn_sched_barrier(0);                                         \
  }

#define GEMM3_MAINLOOP(A_, B_)                                                 \
    __shared__ __attribute__((aligned(16))) char lds[147456];                  \
    const int tid = threadIdx.x;                                               \
    const int lane = tid & 63, wave = tid >> 6;                                \
    const int g = lane >> 4, r15 = lane & 15;                                  \
    const int wm = wave >> 2, wn = wave & 3;                                   \
    const int tid16 = tid << 4;                                                \
    const int rowL = tid16 >> 7;                                               \
    const int swzL = ((((tid16 >> 4) & 7) ^ (rowL & 7)) << 4);                 \
    const char* srcA = (const char*)(A_) + (size_t)(bm + rowL) * 4096 + swzL;  \
    const char* srcB = (const char*)(B_) + (size_t)(bn + rowL) * 4096 + swzL;  \
    f32x4 acc[4][4] = {};                                                      \
    bf16x8 af[4], bfr[4];                                                      \
    STG_TILE(0, 0) STG_TILE(1, 128)                                            \
    asm volatile("s_waitcnt vmcnt(6)" ::: "memory");                           \
    __builtin_amdgcn_sched_barrier(0);                                         \
    __builtin_amdgcn_s_barrier();                                              \
    asm volatile("" ::: "memory");                                             \
    for (int t3 = 0; t3 < 10; ++t3) {                                          \
        const int kb = t3 * 384;                                               \
        DO_TILE(0, 2, kb, 1, 6)                                                \
        DO_TILE(1, 0, kb + 128, 1, 6)                                          \
        DO_TILE(2, 1, kb + 256, 1, 6)                                          \
    }                                                                          \
    DO_TILE(0, 2, 3840, 0, 0)                                                  \
    DO_TILE(1, 0, 3968, 0, -1)

// QKV GEMM: M=4096 (b*2048+t), N=6144 (which*2048 + h*128 + d). grid 768.
// XCD chunking: xcd covers 8bm x 12bn; within, rounds of 8bm x 4bn.
__global__ __launch_bounds__(512) void k_gemm_qkv(
    const s16b* __restrict__ A, const s16b* __restrict__ Bt,
    s16b* __restrict__ Qb, s16b* __restrict__ Kb, s16b* __restrict__ Vt) {
    const int bid = blockIdx.x;
    const int xcd = bid & 7, local = bid >> 3;          // local 0..95
    const int rr_ = local >> 5, w = local & 31;
    const int bm = ((xcd & 3) * 8 + (w >> 2)) * 128;
    const int bn = ((xcd >> 2) * 12 + rr_ * 4 + (w & 3)) * 256;
    GEMM3_MAINLOOP(A, Bt)
#pragma unroll
    for (int i = 0; i < 4; ++i) {
        int m0 = bm + (i >> 1) * 64 + wm * 32 + (i & 1) * 16 + 4 * g;
        int b = m0 >> 11, t0 = m0 & 2047;
#pragma unroll
        for (int j = 0; j < 4; ++j) {
            int n = bn + (j >> 1) * 128 + wn * 32 + (j & 1) * 16 + r15;
            int which = n >> 11;
            int h = (n >> 7) & 15, d = n & 127;
            size_t bh = (size_t)(b * 16 + h);
            if (which == 0) {
                size_t base = (bh * 2048 + t0) * 128 + d;
#pragma unroll
                for (int e = 0; e < 4; ++e) Qb[base + (size_t)e * 128] = f2bf(acc[i][j][e]);
            } else if (which == 1) {
                size_t base = (bh * 2048 + t0) * 128 + d;
#pragma unroll
                for (int e = 0; e < 4; ++e) Kb[base + (size_t)e * 128] = f2bf(acc[i][j][e]);
            } else {
                int pt = (t0 & ~31) + perm32(t0 & 31);   // t-permuted, 4-aligned
                size_t base = (bh * 128 + d) * 2048 + pt;
                bf16x4 pk;
#pragma unroll
                for (int e = 0; e < 4; ++e) pk[e] = f2bf(acc[i][j][e]);
                *(bf16x4*)(Vt + base) = pk;
            }
        }
    }
}

// Proj GEMM: M=4096, N=2048, fp32 out. grid 256 (one full CU round).
__global__ __launch_bounds__(512) void k_gemm_proj(
    const s16b* __restrict__ A, const s16b* __restrict__ Bt, float* __restrict__ Co) {
    const int bid = blockIdx.x;
    const int xcd = bid & 7, local = bid >> 3;          // local 0..31
    const int bm = (xcd * 4 + (local & 3)) * 128;
    const int bn = (local >> 2) * 256;
    GEMM3_MAINLOOP(A, Bt)
#pragma unroll
    for (int i = 0; i < 4; ++i) {
        int m0 = bm + (i >> 1) * 64 + wm * 32 + (i & 1) * 16 + 4 * g;
#pragma unroll
        for (int j = 0; j < 4; ++j) {
            int n = bn + (j >> 1) * 128 + wn * 32 + (j & 1) * 16 + r15;
#pragma unroll
            for (int e = 0; e < 4; ++e) Co[(size_t)(m0 + e) * 2048 + n] = acc[i][j][e];
        }
    }
}

// ---------------- RoPE: Q in place (plain); K -> Kp (d-permuted) ----------------
__global__ void k_rope(s16b* __restrict__ Qb, const s16b* __restrict__ Kb,
                       s16b* __restrict__ Kp,
                       const float* __restrict__ ctab, const float* __restrict__ stab) {
    int idx = blockIdx.x * 256 + threadIdx.x;   // 2*32*2048*16 = 2097152
    int i4 = idx & 15;
    int t = (idx >> 4) & 2047;
    int bh = (idx >> 15) & 31;
    int which = idx >> 20;
    int d = i4 * 4;                 // [0,64)
    const float* cp = ctab + t * 64 + d;
    const float* sp = stab + t * 64 + d;
    size_t rowoff = ((size_t)bh * 2048 + t) * 128;
    if (which == 0) {               // Q in place
        s16b* P = Qb + rowoff;
        bf16x4 a = *(bf16x4*)(P + d);
        bf16x4 bv = *(bf16x4*)(P + d + 64);
        bf16x4 ra, rb;
#pragma unroll
        for (int e = 0; e < 4; ++e) {
            float c = cp[e], s = sp[e];
            float x1 = bf2f(a[e]), x2 = bf2f(bv[e]);
            ra[e] = f2bf(x1 * c - x2 * s);
            rb[e] = f2bf(x2 * c + x1 * s);
        }
        *(bf16x4*)(P + d) = ra;
        *(bf16x4*)(P + d + 64) = rb;
    } else {                        // K: read plain, write permuted
        const s16b* Pi = Kb + rowoff;
        s16b* Po = Kp + rowoff;
        bf16x4 a = *(const bf16x4*)(Pi + d);
        bf16x4 bv = *(const bf16x4*)(Pi + d + 64);
        bf16x4 ra, rb;
#pragma unroll
        for (int e = 0; e < 4; ++e) {
            float c = cp[e], s = sp[e];
            float x1 = bf2f(a[e]), x2 = bf2f(bv[e]);
            ra[e] = f2bf(x1 * c - x2 * s);
            rb[e] = f2bf(x2 * c + x1 * s);
        }
        int d2 = d + 64;
        int pd  = (d  & ~31) + perm32(d  & 31);
        int pd2 = (d2 & ~31) + perm32(d2 & 31);
        *(bf16x4*)(Po + pd) = ra;
        *(bf16x4*)(Po + pd2) = rb;
    }
}

// ---------------- Flash attention (swapped QK^T, causal) ----------------
// grid (32 bh, 16 qtiles; qt = 15 - blockIdx.y so heavy blocks dispatch first).
__global__ __launch_bounds__(256) void k_attn(
    const s16b* __restrict__ Qb, const s16b* __restrict__ Kp,
    const s16b* __restrict__ Vt, s16b* __restrict__ AO) {
    __shared__ alignas(16) s16b Ks[64 * 128];   // [k][d-perm], 256B rows, 16 slots
    __shared__ alignas(16) s16b Vs[128 * 64];   // [d][t-perm], 128B rows, 8 slots
    const int tid = threadIdx.x;
    const int lane = tid & 63, wave = tid >> 6;
    const int g = lane >> 4, r15 = lane & 15;
    const int bh = blockIdx.x, qt = 15 - blockIdx.y;
    const int q0 = qt * 128 + wave * 32;
    const s16b* Qg = Qb + (size_t)bh * 2048 * 128;
    const char* Kg = (const char*)(Kp + (size_t)bh * 2048 * 128);
    const char* Vg = (const char*)(Vt + (size_t)bh * 128 * 2048);

    // hoist Q fragments (B-operand; global plain layout, 2x8B each)
    bf16x8 qf[2][4];
#pragma unroll
    for (int qs = 0; qs < 2; ++qs)
#pragma unroll
        for (int ds = 0; ds < 4; ++ds) {
            const s16b* p = Qg + (size_t)(q0 + qs * 16 + r15) * 128 + ds * 32 + 4 * g;
            bf16x4 lo = *(const bf16x4*)p;
            bf16x4 hi = *(const bf16x4*)(p + 16);
            qf[qs][ds] = __builtin_shufflevector(lo, hi, 0, 1, 2, 3, 4, 5, 6, 7);
        }

    f32x4 ot[8][2] = {};               // O^T accs: [dsub][qsub]
    float m_s[2] = {-3e38f, -3e38f};
    float l_s[2] = {0.f, 0.f};
    const float scale = 0.0883883476483184f;   // 1/sqrt(128)

    const int ktiles = qt * 2 + 2;
    for (int kt = 0; kt < ktiles; ++kt) {
        const int k0 = kt * 64;
        __syncthreads();
#pragma unroll
        for (int rr = 0; rr < 4; ++rr) {
            int uo = (rr * 256 + wave * 64) * 16;
            int o = uo + lane * 16;
            {   // K tile: 256B rows, 16 slots, swizzle low 3 slot bits
                int row = o >> 8, sl = (o >> 4) & 15;
                int sg = (sl ^ (row & 7)) << 4;
                gload_lds16(Kg + (size_t)(k0 + row) * 256 + sg, (char*)Ks + uo);
            }
            {   // V^T tile: 128B rows, 8 slots
                int row = o >> 7, sl = (o >> 4) & 7;
                int sg = (sl ^ (row & 7)) << 4;
                gload_lds16(Vg + (size_t)row * 4096 + (size_t)k0 * 2 + sg, (char*)Vs + uo);
            }
        }
        __syncthreads();

        if (k0 <= q0 + 31) {   // wave-uniform causal skip
            // S^T = K . Q^T   (rows = k, cols = q)
            f32x4 st[4][2] = {};
            __builtin_amdgcn_s_setprio(1);
#pragma unroll
            for (int ds = 0; ds < 4; ++ds) {
#pragma unroll
                for (int ks = 0; ks < 4; ++ks) {
                    bf16x8 kf = lds256(Ks, ks * 16 + r15, ds, g);
#pragma unroll
                    for (int qs = 0; qs < 2; ++qs)
                        st[ks][qs] = mfma16(kf, qf[qs][ds], st[ks][qs]);
                }
            }
            __builtin_amdgcn_s_setprio(0);
            // scale + causal mask
#pragma unroll
            for (int ks = 0; ks < 4; ++ks)
#pragma unroll
                for (int qs = 0; qs < 2; ++qs)
#pragma unroll
                    for (int e = 0; e < 4; ++e) {
                        int kk = k0 + ks * 16 + 4 * g + e;
                        int qq = q0 + qs * 16 + r15;
                        float s = st[ks][qs][e] * scale;
                        st[ks][qs][e] = (kk <= qq) ? s : -3e38f;
                    }
            // online softmax per q-column (lane-local + 2 shfl_xor)
            float sf[2];
#pragma unroll
            for (int qs = 0; qs < 2; ++qs) {
                float mx = -3e38f;
#pragma unroll
                for (int ks = 0; ks < 4; ++ks)
#pragma unroll
                    for (int e = 0; e < 4; ++e) mx = fmaxf(mx, st[ks][qs][e]);
                mx = fmaxf(mx, __shfl_xor(mx, 16));
                mx = fmaxf(mx, __shfl_xor(mx, 32));
                float mn = fmaxf(m_s[qs], mx);
                sf[qs] = __expf(m_s[qs] - mn);
                m_s[qs] = mn;
                float sum = 0.f;
#pragma unroll
                for (int ks = 0; ks < 4; ++ks)
#pragma unroll
                    for (int e = 0; e < 4; ++e) {
                        float p = __expf(st[ks][qs][e] - mn);
                        st[ks][qs][e] = p;
                        sum += p;
                    }
                sum += __shfl_xor(sum, 16);
                sum += __shfl_xor(sum, 32);
                l_s[qs] = l_s[qs] * sf[qs] + sum;
            }
            // P -> bf16 B-frags (register-only; C/D layout == B-operand layout)
            bf16x8 pb[2][2];
#pragma unroll
            for (int k2 = 0; k2 < 2; ++k2)
#pragma unroll
                for (int qs = 0; qs < 2; ++qs) {
                    bf16x8 f;
#pragma unroll
                    for (int jj = 0; jj < 8; ++jj)
                        f[jj] = f2bf(st[2 * k2 + (jj >> 2)][qs][jj & 3]);
                    pb[k2][qs] = f;
                }
            // rescale O
#pragma unroll
            for (int d8 = 0; d8 < 8; ++d8)
#pragma unroll
                for (int qs = 0; qs < 2; ++qs)
#pragma unroll
                    for (int e = 0; e < 4; ++e) ot[d8][qs][e] *= sf[qs];
            // O^T += V^T . P^T
            __builtin_amdgcn_s_setprio(1);
#pragma unroll
            for (int k2 = 0; k2 < 2; ++k2)
#pragma unroll
                for (int d8 = 0; d8 < 8; ++d8) {
                    bf16x8 vf = lds128(Vs, d8 * 16 + r15, k2, g);
#pragma unroll
                    for (int qs = 0; qs < 2; ++qs)
                        ot[d8][qs] = mfma16(vf, pb[k2][qs], ot[d8][qs]);
                }
            __builtin_amdgcn_s_setprio(0);
        }
    }
    // write AO [B,T,C] with C-permuted columns (proj GEMM A-operand layout)
    int b = bh >> 4, h = bh & 15;
#pragma unroll
    for (int qs = 0; qs < 2; ++qs) {
        float inv = 1.0f / l_s[qs];
        int q = q0 + qs * 16 + r15;
#pragma unroll
        for (int d8 = 0; d8 < 8; ++d8) {
            bf16x4 pk;
#pragma unroll
            for (int e = 0; e < 4; ++e) pk[e] = f2bf(ot[d8][qs][e] * inv);
            size_t off = ((size_t)(b * 2048 + q)) * 2048
                       + h * 128 + (d8 >> 1) * 32 + g * 8 + (d8 & 1) * 4;
            *(bf16x4*)(AO + off) = pk;
        }
    }
}

extern "C" void kernel_launch(void* const* d_in, const int* in_sizes, int n_in,
                              void* d_out, int out_size, void* d_ws, size_t ws_size,
                              hipStream_t stream) {
    const float* x = (const float*)d_in[0];
    const float* Wqkv = (const float*)d_in[1];
    const float* Wproj = (const float*)d_in[2];
    float* out = (float*)d_out;

    char* ws = (char*)d_ws;
    float* ctab = (float*)ws;
    float* stab = ctab + 2048 * 64;
    size_t off = 1048576;
    s16b* xb = (s16b*)(ws + off); off += 16777216;        // x bf16 K-perm; reused as AO
    s16b* wqkvt = (s16b*)(ws + off); off += 25165824;     // [6144][2048] bf16 K-perm; reused as Kp
    s16b* wprojt = (s16b*)(ws + off); off += 8388608;     // [2048][2048] bf16 K-perm
    s16b* Qb = (s16b*)(ws + off); off += 16777216;        // [2,16,2048,128] plain
    s16b* Kb = (s16b*)(ws + off); off += 16777216;        // plain (pre-RoPE)
    s16b* Vt = (s16b*)(ws + off); off += 16777216;        // [2,16,128,2048] t-perm
    s16b* AO = xb;      // alias: xb dead after QKV GEMM
    s16b* Kp = wqkvt;   // alias: wqkvt dead after QKV GEMM (RoPE'd K, d-perm)

    k_tables<<<dim3(512), dim3(256), 0, stream>>>(ctab, stab);
    k_cvt_x<<<dim3(8192), dim3(256), 0, stream>>>(x, xb);
    k_tcvt<<<dim3(192, 64), dim3(256), 0, stream>>>(Wqkv, wqkvt, 2048, 6144);
    k_tcvt<<<dim3(64, 64), dim3(256), 0, stream>>>(Wproj, wprojt, 2048, 2048);
    k_gemm_qkv<<<dim3(768), dim3(512), 0, stream>>>(xb, wqkvt, Qb, Kb, Vt);
    k_rope<<<dim3(8192), dim3(256), 0, stream>>>(Qb, Kb, Kp, ctab, stab);
    k_attn<<<dim3(32, 16), dim3(256), 0, stream>>>(Qb, Kp, Vt, AO);
    k_gemm_proj<<<dim3(256), dim3(512), 0, stream>>>(AO, wprojt, out);
}

// Round 6
// 270.180 us; speedup vs baseline: 1.8173x; 1.0106x over previous
//
#include <hip/hip_runtime.h>
#include <hip/hip_bf16.h>

typedef short s16b;
using bf16x4 = __attribute__((ext_vector_type(4))) short;
using bf16x8 = __attribute__((ext_vector_type(8))) short;
using f32x4  = __attribute__((ext_vector_type(4))) float;

#define DEVINL __device__ __forceinline__

DEVINL float bf2f(short u) {
    union { float f; unsigned u; } x;
    x.u = ((unsigned)(unsigned short)u) << 16;
    return x.f;
}
DEVINL short f2bf(float f) {   // round-to-nearest-even
    unsigned u = __builtin_bit_cast(unsigned, f);
    u += 0x7FFFu + ((u >> 16) & 1u);
    return (short)(u >> 16);
}

DEVINL f32x4 mfma16(bf16x8 a, bf16x8 b, f32x4 c) {
    return __builtin_amdgcn_mfma_f32_16x16x32_bf16(a, b, c, 0, 0, 0);
}

DEVINL void gload_lds16(const void* g, void* lds_uniform) {
    __builtin_amdgcn_global_load_lds(
        (const __attribute__((address_space(1))) char*)(const char*)g,
        (__attribute__((address_space(3))) char*)(char*)lds_uniform, 16, 0, 0);
}

// stored position of k within a 32-element K-group:
// chunk order [0-3,16-19,4-7,20-23,8-11,24-27,12-15,28-31]
DEVINL int perm32(int k) {
    return ((k >> 2) & 3) * 8 + ((k >> 4) & 1) * 4 + (k & 3);
}

// LDS frag read, 128B rows, 8 slots of 16B, swizzle slot^=(row&7). (attn kernel)
DEVINL bf16x8 lds128(const s16b* base, int row, int ks, int g) {
    const char* p = (const char*)base + row * 128 + ((((ks << 2) + g) ^ (row & 7)) << 4);
    return *(const bf16x8*)p;
}
// LDS frag read, 256B rows, 16 slots, swizzle low 3 slot bits.
DEVINL bf16x8 lds256(const s16b* base, int row, int ds, int g) {
    const char* p = (const char*)base + row * 256 + ((((ds << 2) + g) ^ (row & 7)) << 4);
    return *(const bf16x8*)p;
}

// ---------------- RoPE tables: cos/sin [2048][64] fp32 ----------------
__global__ void k_tables(float* __restrict__ ctab, float* __restrict__ stab) {
    int idx = blockIdx.x * 256 + threadIdx.x;      // 2048*64 = 131072
    int i = idx & 63, t = idx >> 6;
    float inv = powf(10000.0f, -(float)i * (1.0f / 64.0f));
    float fr = (float)t * inv;
    ctab[idx] = cosf(fr);
    stab[idx] = sinf(fr);
}

// ---------------- x fp32 -> bf16, K-permuted rows ----------------
__global__ void k_cvt_x(const float* __restrict__ x, s16b* __restrict__ xb) {
    int idx = blockIdx.x * 256 + threadIdx.x;        // 2097152 threads, 4 elems each
    int p = idx * 4;                                  // stored position
    int row = p >> 11, pc = p & 2047;
    int grp = pc >> 5, sp = pc & 31;
    int c = sp >> 3, half = (sp >> 2) & 1;
    int ksrc = grp * 32 + half * 16 + c * 4;          // source k (4 contiguous)
    float4 v = *(const float4*)(x + (size_t)row * 2048 + ksrc);
    bf16x4 o;
    o[0] = f2bf(v.x); o[1] = f2bf(v.y); o[2] = f2bf(v.z); o[3] = f2bf(v.w);
    *(bf16x4*)(xb + (size_t)row * 2048 + pc) = o;
}

// ---------------- W [R][C] fp32 -> Wt [C][R] bf16, K(=R)-permuted ----------------
__global__ void k_tcvt(const float* __restrict__ in, s16b* __restrict__ out, int R, int C) {
    __shared__ float tile[32][33];
    int tx = threadIdx.x & 31, ty = threadIdx.x >> 5;   // 32 x 8
    int c0 = blockIdx.x * 32, r0 = blockIdx.y * 32;     // r0 multiple of 32
#pragma unroll
    for (int kk = 0; kk < 4; ++kk) {
        int r = ty + kk * 8;
        tile[r][tx] = in[(size_t)(r0 + r) * C + c0 + tx];
    }
    __syncthreads();
#pragma unroll
    for (int kk = 0; kk < 4; ++kk) {
        int r = ty + kk * 8;
        out[(size_t)(c0 + r) * R + r0 + perm32(tx)] = f2bf(tile[tx][r]);
    }
}

// ======= Fine-phase tribuf GEMM: BM=128, BN=256, BK=64, 8 waves =======
// LDS 144KB: A bufs 16KB @ 0/16384/32768 (128 rows x 128B, 8-slot XOR row&7)
//            B bufs 32KB @ 49152/81920/114688 (256 rows x 128B)
// Tile tau in buf tau%3; during tau stage tile tau+2 (6 loads spread p0-p2).
// 4 phases/tile (kh,jh), each: {ds_read af4?/bf2 | stage 2 | [vmcnt@p3] |
//   barrier | lgkmcnt(0) | setprio 8xMFMA | barrier}.  vmcnt(6)@p3 retires
// tile tau+1's 6 loads (issued during tau-1); tile30 p3 drains to 0.
#define STG_B01(DB, KB)                                                        \
  gload_lds16(srcB + (KB), lds + 49152 + (DB) * 32768 + tid16);                \
  gload_lds16(srcB + 262144 + (KB), lds + 49152 + (DB) * 32768 + 8192 + tid16);
#define STG_B23(DB, KB)                                                        \
  gload_lds16(srcB + 524288 + (KB), lds + 49152 + (DB) * 32768 + 16384 + tid16); \
  gload_lds16(srcB + 786432 + (KB), lds + 49152 + (DB) * 32768 + 24576 + tid16);
#define STG_A01(DB, KB)                                                        \
  gload_lds16(srcA + (KB), lds + (DB) * 16384 + tid16);                        \
  gload_lds16(srcA + 262144 + (KB), lds + (DB) * 16384 + 8192 + tid16);

#define AF_READ(B, KS)                                                         \
    _Pragma("unroll")                                                          \
    for (int fi = 0; fi < 4; ++fi) {                                           \
      int row = (fi >> 1) * 64 + wm * 32 + (fi & 1) * 16 + r15;                \
      af[fi] = *(const bf16x8*)(lds + (B) * 16384 + row * 128                  \
               + ((((KS) * 4 + g) ^ (row & 7)) << 4));                         \
    }

#define PH4(B, KH, JH, STGC, WN)                                               \
  {                                                                            \
    if ((JH) == 0) { AF_READ(B, KH) }                                          \
    _Pragma("unroll")                                                          \
    for (int fj = 0; fj < 2; ++fj) {                                           \
      int row = (JH) * 128 + wn * 32 + fj * 16 + r15;                          \
      bfr[fj] = *(const bf16x8*)(lds + 49152 + (B) * 32768 + row * 128         \
                + ((((KH) * 4 + g) ^ (row & 7)) << 4));                        \
    }                                                                          \
    STGC                                                                       \
    if ((WN) == 6) { asm volatile("s_waitcnt vmcnt(6)" ::: "memory");          \
                     __builtin_amdgcn_sched_barrier(0); }                      \
    else if ((WN) == 0) { asm volatile("s_waitcnt vmcnt(0)" ::: "memory");     \
                     __builtin_amdgcn_sched_barrier(0); }                      \
    __builtin_amdgcn_s_barrier();                                              \
    asm volatile("s_waitcnt lgkmcnt(0)" ::: "memory");                         \
    __builtin_amdgcn_sched_barrier(0);                                         \
    __builtin_amdgcn_s_setprio(1);                                             \
    _Pragma("unroll")                                                          \
    for (int fi = 0; fi < 4; ++fi)                                             \
      _Pragma("unroll")                                                        \
      for (int fj = 0; fj < 2; ++fj)                                           \
        acc[fi][(JH) * 2 + fj] = mfma16(af[fi], bfr[fj], acc[fi][(JH) * 2 + fj]); \
    __builtin_amdgcn_s_setprio(0);                                             \
    __builtin_amdgcn_s_barrier();                                              \
    __builtin_amdgcn_sched_barrier(0);                                         \
  }

#define DO_TILE3(B, S1, S2, S3, WNL)                                           \
    PH4(B, 0, 0, S1, -1)                                                       \
    PH4(B, 0, 1, S2, -1)                                                       \
    PH4(B, 1, 0, S3, -1)                                                       \
    PH4(B, 1, 1, , WNL)

#define GEMM3_MAINLOOP(A_, B_)                                                 \
    __shared__ __attribute__((aligned(16))) char lds[147456];                  \
    const int tid = threadIdx.x;                                               \
    const int lane = tid & 63, wave = tid >> 6;                                \
    const int g = lane >> 4, r15 = lane & 15;                                  \
    const int wm = wave >> 2, wn = wave & 3;                                   \
    const int tid16 = tid << 4;                                                \
    const int rowL = tid16 >> 7;                                               \
    const int swzL = ((((tid16 >> 4) & 7) ^ (rowL & 7)) << 4);                 \
    const char* srcA = (const char*)(A_) + (size_t)(bm + rowL) * 4096 + swzL;  \
    const char* srcB = (const char*)(B_) + (size_t)(bn + rowL) * 4096 + swzL;  \
    f32x4 acc[4][4] = {};                                                      \
    bf16x8 af[4], bfr[2];                                                      \
    STG_B01(0, 0) STG_A01(0, 0) STG_B23(0, 0)                                  \
    STG_B01(1, 128) STG_A01(1, 128) STG_B23(1, 128)                            \
    asm volatile("s_waitcnt vmcnt(6)" ::: "memory");                           \
    __builtin_amdgcn_sched_barrier(0);                                         \
    __builtin_amdgcn_s_barrier();                                              \
    for (int t3 = 0; t3 < 10; ++t3) {                                          \
        const int kb2 = (3 * t3 + 2) * 128;                                    \
        const int kb3 = kb2 + 128, kb4 = kb2 + 256;                            \
        DO_TILE3(0, STG_B01(2, kb2), STG_A01(2, kb2), STG_B23(2, kb2), 6)      \
        DO_TILE3(1, STG_B01(0, kb3), STG_A01(0, kb3), STG_B23(0, kb3), 6)      \
        DO_TILE3(2, STG_B01(1, kb4), STG_A01(1, kb4), STG_B23(1, kb4), 6)      \
    }                                                                          \
    DO_TILE3(0, , , , 0)                                                       \
    DO_TILE3(1, , , , -1)

// QKV GEMM: M=4096 (b*2048+t), N=6144 (which*2048 + h*128 + d). grid 768.
// XCD chunking: xcd covers 8bm x 12bn.
__global__ __launch_bounds__(512) void k_gemm_qkv(
    const s16b* __restrict__ A, const s16b* __restrict__ Bt,
    s16b* __restrict__ Qb, s16b* __restrict__ Kb, s16b* __restrict__ Vt) {
    const int bid = blockIdx.x;
    const int xcd = bid & 7, local = bid >> 3;          // local 0..95
    const int rr_ = local >> 5, w = local & 31;
    const int bm = ((xcd & 3) * 8 + (w >> 2)) * 128;
    const int bn = ((xcd >> 2) * 12 + rr_ * 4 + (w & 3)) * 256;
    GEMM3_MAINLOOP(A, Bt)
    const int which = bn >> 11;                          // block-uniform
    if (which < 2) {
        // ---- coalesced Q/K store via LDS transpose ----
        s16b* dst = which ? Kb : Qb;
        char* sml = (char*)lds;
#pragma unroll
        for (int i = 0; i < 4; ++i) {
#pragma unroll
            for (int j = 0; j < 4; ++j) {
                int mb0 = (i >> 1) * 64 + wm * 32 + (i & 1) * 16 + 4 * g;
                int nn = (j >> 1) * 128 + wn * 32 + (j & 1) * 16 + r15;
#pragma unroll
                for (int e = 0; e < 4; ++e) {
                    int mm = mb0 + e;
                    *(s16b*)(sml + mm * 528 + ((nn * 2) ^ ((mm & 3) << 5))) =
                        f2bf(acc[i][j][e]);
                }
            }
        }
        __syncthreads();
        const int mrow = tid >> 2, c4 = tid & 3;
        const int bb = bm >> 11;
        const int tt = (bm & 2047) + mrow;
        const char* srow = sml + mrow * 528;
        const int sw = (mrow & 3) << 5;
#pragma unroll
        for (int k = 0; k < 8; ++k) {
            int lc = c4 + 4 * k;                 // logical 16B chunk, n0 = lc*8
            bf16x8 v = *(const bf16x8*)(srow + ((lc * 16) ^ sw));
            int ng = bn + lc * 8;
            int h = (ng >> 7) & 15, d = ng & 127;
            *(bf16x8*)(dst + ((size_t)(bb * 16 + h) * 2048 + tt) * 128 + d) = v;
        }
    } else {
        // ---- V: [B,H,D,T] t-permuted, bf16x4 writes (as before) ----
#pragma unroll
        for (int i = 0; i < 4; ++i) {
            int m0 = bm + (i >> 1) * 64 + wm * 32 + (i & 1) * 16 + 4 * g;
            int b = m0 >> 11, t0 = m0 & 2047;
#pragma unroll
            for (int j = 0; j < 4; ++j) {
                int n = bn + (j >> 1) * 128 + wn * 32 + (j & 1) * 16 + r15;
                int h = (n >> 7) & 15, d = n & 127;
                size_t bh = (size_t)(b * 16 + h);
                int pt = (t0 & ~31) + perm32(t0 & 31);
                size_t base = (bh * 128 + d) * 2048 + pt;
                bf16x4 pk;
#pragma unroll
                for (int e = 0; e < 4; ++e) pk[e] = f2bf(acc[i][j][e]);
                *(bf16x4*)(Vt + base) = pk;
            }
        }
    }
}

// Proj GEMM: M=4096, N=2048, fp32 out (line-coalesced 4B stores). grid 256.
__global__ __launch_bounds__(512) void k_gemm_proj(
    const s16b* __restrict__ A, const s16b* __restrict__ Bt, float* __restrict__ Co) {
    const int bid = blockIdx.x;
    const int xcd = bid & 7, local = bid >> 3;          // local 0..31
    const int bm = (xcd * 4 + (local & 3)) * 128;
    const int bn = (local >> 2) * 256;
    GEMM3_MAINLOOP(A, Bt)
#pragma unroll
    for (int i = 0; i < 4; ++i) {
        int m0 = bm + (i >> 1) * 64 + wm * 32 + (i & 1) * 16 + 4 * g;
#pragma unroll
        for (int j = 0; j < 4; ++j) {
            int n = bn + (j >> 1) * 128 + wn * 32 + (j & 1) * 16 + r15;
#pragma unroll
            for (int e = 0; e < 4; ++e) Co[(size_t)(m0 + e) * 2048 + n] = acc[i][j][e];
        }
    }
}

// ---------------- RoPE: Q in place (plain); K -> Kp (d-permuted) ----------------
__global__ void k_rope(s16b* __restrict__ Qb, const s16b* __restrict__ Kb,
                       s16b* __restrict__ Kp,
                       const float* __restrict__ ctab, const float* __restrict__ stab) {
    int idx = blockIdx.x * 256 + threadIdx.x;   // 2*32*2048*16 = 2097152
    int i4 = idx & 15;
    int t = (idx >> 4) & 2047;
    int bh = (idx >> 15) & 31;
    int which = idx >> 20;
    int d = i4 * 4;                 // [0,64)
    const float* cp = ctab + t * 64 + d;
    const float* sp = stab + t * 64 + d;
    size_t rowoff = ((size_t)bh * 2048 + t) * 128;
    if (which == 0) {               // Q in place
        s16b* P = Qb + rowoff;
        bf16x4 a = *(bf16x4*)(P + d);
        bf16x4 bv = *(bf16x4*)(P + d + 64);
        bf16x4 ra, rb;
#pragma unroll
        for (int e = 0; e < 4; ++e) {
            float c = cp[e], s = sp[e];
            float x1 = bf2f(a[e]), x2 = bf2f(bv[e]);
            ra[e] = f2bf(x1 * c - x2 * s);
            rb[e] = f2bf(x2 * c + x1 * s);
        }
        *(bf16x4*)(P + d) = ra;
        *(bf16x4*)(P + d + 64) = rb;
    } else {                        // K: read plain, write permuted
        const s16b* Pi = Kb + rowoff;
        s16b* Po = Kp + rowoff;
        bf16x4 a = *(const bf16x4*)(Pi + d);
        bf16x4 bv = *(const bf16x4*)(Pi + d + 64);
        bf16x4 ra, rb;
#pragma unroll
        for (int e = 0; e < 4; ++e) {
            float c = cp[e], s = sp[e];
            float x1 = bf2f(a[e]), x2 = bf2f(bv[e]);
            ra[e] = f2bf(x1 * c - x2 * s);
            rb[e] = f2bf(x2 * c + x1 * s);
        }
        int d2 = d + 64;
        int pd  = (d  & ~31) + perm32(d  & 31);
        int pd2 = (d2 & ~31) + perm32(d2 & 31);
        *(bf16x4*)(Po + pd) = ra;
        *(bf16x4*)(Po + pd2) = rb;
    }
}

// ---------------- Flash attention (swapped QK^T, causal) ----------------
// grid (32 bh, 16 qtiles; qt = 15 - blockIdx.y so heavy blocks dispatch first).
__global__ __launch_bounds__(256) void k_attn(
    const s16b* __restrict__ Qb, const s16b* __restrict__ Kp,
    const s16b* __restrict__ Vt, s16b* __restrict__ AO) {
    __shared__ alignas(16) s16b Ks[64 * 128];   // [k][d-perm], 256B rows, 16 slots
    __shared__ alignas(16) s16b Vs[128 * 64];   // [d][t-perm], 128B rows, 8 slots
    const int tid = threadIdx.x;
    const int lane = tid & 63, wave = tid >> 6;
    const int g = lane >> 4, r15 = lane & 15;
    const int bh = blockIdx.x, qt = 15 - blockIdx.y;
    const int q0 = qt * 128 + wave * 32;
    const s16b* Qg = Qb + (size_t)bh * 2048 * 128;
    const char* Kg = (const char*)(Kp + (size_t)bh * 2048 * 128);
    const char* Vg = (const char*)(Vt + (size_t)bh * 128 * 2048);

    // hoist Q fragments (B-operand; global plain layout, 2x8B each)
    bf16x8 qf[2][4];
#pragma unroll
    for (int qs = 0; qs < 2; ++qs)
#pragma unroll
        for (int ds = 0; ds < 4; ++ds) {
            const s16b* p = Qg + (size_t)(q0 + qs * 16 + r15) * 128 + ds * 32 + 4 * g;
            bf16x4 lo = *(const bf16x4*)p;
            bf16x4 hi = *(const bf16x4*)(p + 16);
            qf[qs][ds] = __builtin_shufflevector(lo, hi, 0, 1, 2, 3, 4, 5, 6, 7);
        }

    f32x4 ot[8][2] = {};               // O^T accs: [dsub][qsub]
    float m_s[2] = {-3e38f, -3e38f};
    float l_s[2] = {0.f, 0.f};
    const float scale = 0.0883883476483184f;   // 1/sqrt(128)

    const int ktiles = qt * 2 + 2;
    for (int kt = 0; kt < ktiles; ++kt) {
        const int k0 = kt * 64;
        __syncthreads();
#pragma unroll
        for (int rr = 0; rr < 4; ++rr) {
            int uo = (rr * 256 + wave * 64) * 16;
            int o = uo + lane * 16;
            {   // K tile: 256B rows, 16 slots, swizzle low 3 slot bits
                int row = o >> 8, sl = (o >> 4) & 15;
                int sg = (sl ^ (row & 7)) << 4;
                gload_lds16(Kg + (size_t)(k0 + row) * 256 + sg, (char*)Ks + uo);
            }
            {   // V^T tile: 128B rows, 8 slots
                int row = o >> 7, sl = (o >> 4) & 7;
                int sg = (sl ^ (row & 7)) << 4;
                gload_lds16(Vg + (size_t)row * 4096 + (size_t)k0 * 2 + sg, (char*)Vs + uo);
            }
        }
        __syncthreads();

        if (k0 <= q0 + 31) {   // wave-uniform causal skip
            // S^T = K . Q^T   (rows = k, cols = q)
            f32x4 st[4][2] = {};
            __builtin_amdgcn_s_setprio(1);
#pragma unroll
            for (int ds = 0; ds < 4; ++ds) {
#pragma unroll
                for (int ks = 0; ks < 4; ++ks) {
                    bf16x8 kf = lds256(Ks, ks * 16 + r15, ds, g);
#pragma unroll
                    for (int qs = 0; qs < 2; ++qs)
                        st[ks][qs] = mfma16(kf, qf[qs][ds], st[ks][qs]);
                }
            }
            __builtin_amdgcn_s_setprio(0);
            // scale + causal mask
#pragma unroll
            for (int ks = 0; ks < 4; ++ks)
#pragma unroll
                for (int qs = 0; qs < 2; ++qs)
#pragma unroll
                    for (int e = 0; e < 4; ++e) {
                        int kk = k0 + ks * 16 + 4 * g + e;
                        int qq = q0 + qs * 16 + r15;
                        float s = st[ks][qs][e] * scale;
                        st[ks][qs][e] = (kk <= qq) ? s : -3e38f;
                    }
            // online softmax per q-column (lane-local + 2 shfl_xor)
            float sf[2];
#pragma unroll
            for (int qs = 0; qs < 2; ++qs) {
                float mx = -3e38f;
#pragma unroll
                for (int ks = 0; ks < 4; ++ks)
#pragma unroll
                    for (int e = 0; e < 4; ++e) mx = fmaxf(mx, st[ks][qs][e]);
                mx = fmaxf(mx, __shfl_xor(mx, 16));
                mx = fmaxf(mx, __shfl_xor(mx, 32));
                float mn = fmaxf(m_s[qs], mx);
                sf[qs] = __expf(m_s[qs] - mn);
                m_s[qs] = mn;
                float sum = 0.f;
#pragma unroll
                for (int ks = 0; ks < 4; ++ks)
#pragma unroll
                    for (int e = 0; e < 4; ++e) {
                        float p = __expf(st[ks][qs][e] - mn);
                        st[ks][qs][e] = p;
                        sum += p;
                    }
                sum += __shfl_xor(sum, 16);
                sum += __shfl_xor(sum, 32);
                l_s[qs] = l_s[qs] * sf[qs] + sum;
            }
            // P -> bf16 B-frags (register-only; C/D layout == B-operand layout)
            bf16x8 pb[2][2];
#pragma unroll
            for (int k2 = 0; k2 < 2; ++k2)
#pragma unroll
                for (int qs = 0; qs < 2; ++qs) {
                    bf16x8 f;
#pragma unroll
                    for (int jj = 0; jj < 8; ++jj)
                        f[jj] = f2bf(st[2 * k2 + (jj >> 2)][qs][jj & 3]);
                    pb[k2][qs] = f;
                }
            // rescale O
#pragma unroll
            for (int d8 = 0; d8 < 8; ++d8)
#pragma unroll
                for (int qs = 0; qs < 2; ++qs)
#pragma unroll
                    for (int e = 0; e < 4; ++e) ot[d8][qs][e] *= sf[qs];
            // O^T += V^T . P^T
            __builtin_amdgcn_s_setprio(1);
#pragma unroll
            for (int k2 = 0; k2 < 2; ++k2)
#pragma unroll
                for (int d8 = 0; d8 < 8; ++d8) {
                    bf16x8 vf = lds128(Vs, d8 * 16 + r15, k2, g);
#pragma unroll
                    for (int qs = 0; qs < 2; ++qs)
                        ot[d8][qs] = mfma16(vf, pb[k2][qs], ot[d8][qs]);
                }
            __builtin_amdgcn_s_setprio(0);
        }
    }
    // write AO [B,T,C] with C-permuted columns (proj GEMM A-operand layout)
    int b = bh >> 4, h = bh & 15;
#pragma unroll
    for (int qs = 0; qs < 2; ++qs) {
        float inv = 1.0f / l_s[qs];
        int q = q0 + qs * 16 + r15;
#pragma unroll
        for (int d8 = 0; d8 < 8; ++d8) {
            bf16x4 pk;
#pragma unroll
            for (int e = 0; e < 4; ++e) pk[e] = f2bf(ot[d8][qs][e] * inv);
            size_t off = ((size_t)(b * 2048 + q)) * 2048
                       + h * 128 + (d8 >> 1) * 32 + g * 8 + (d8 & 1) * 4;
            *(bf16x4*)(AO + off) = pk;
        }
    }
}

extern "C" void kernel_launch(void* const* d_in, const int* in_sizes, int n_in,
                              void* d_out, int out_size, void* d_ws, size_t ws_size,
                              hipStream_t stream) {
    const float* x = (const float*)d_in[0];
    const float* Wqkv = (const float*)d_in[1];
    const float* Wproj = (const float*)d_in[2];
    float* out = (float*)d_out;

    char* ws = (char*)d_ws;
    float* ctab = (float*)ws;
    float* stab = ctab + 2048 * 64;
    size_t off = 1048576;
    s16b* xb = (s16b*)(ws + off); off += 16777216;        // x bf16 K-perm; reused as AO
    s16b* wqkvt = (s16b*)(ws + off); off += 25165824;     // [6144][2048] bf16 K-perm; reused as Kp
    s16b* wprojt = (s16b*)(ws + off); off += 8388608;     // [2048][2048] bf16 K-perm
    s16b* Qb = (s16b*)(ws + off); off += 16777216;        // [2,16,2048,128] plain
    s16b* Kb = (s16b*)(ws + off); off += 16777216;        // plain (pre-RoPE)
    s16b* Vt = (s16b*)(ws + off); off += 16777216;        // [2,16,128,2048] t-perm
    s16b* AO = xb;      // alias: xb dead after QKV GEMM
    s16b* Kp = wqkvt;   // alias: wqkvt dead after QKV GEMM (RoPE'd K, d-perm)

    k_tables<<<dim3(512), dim3(256), 0, stream>>>(ctab, stab);
    k_cvt_x<<<dim3(8192), dim3(256), 0, stream>>>(x, xb);
    k_tcvt<<<dim3(192, 64), dim3(256), 0, stream>>>(Wqkv, wqkvt, 2048, 6144);
    k_tcvt<<<dim3(64, 64), dim3(256), 0, stream>>>(Wproj, wprojt, 2048, 2048);
    k_gemm_qkv<<<dim3(768), dim3(512), 0, stream>>>(xb, wqkvt, Qb, Kb, Vt);
    k_rope<<<dim3(8192), dim3(256), 0, stream>>>(Qb, Kb, Kp, ctab, stab);
    k_attn<<<dim3(32, 16), dim3(256), 0, stream>>>(Qb, Kp, Vt, AO);
    k_gemm_proj<<<dim3(256), dim3(512), 0, stream>>>(AO, wprojt, out);
}